// Round 2
// baseline (514.417 us; speedup 1.0000x reference)
//
#include <hip/hip_runtime.h>

#define BN_EPS 1e-5f

// ---------------------------------------------------------------------------
// ws layout (4-byte elements):
//   lin      [n*128] float     (x @ W)
//   h        [n*128] float     (pre-BN activations)
//   deg_i    [n]     int       (zeroed)
//   colsum   [128]   float     (zeroed)
//   colsumsq [128]   float     (zeroed)
//   row_start[n+1]   int       (CSR offsets, written by scan)
//   cursor   [n]     int       (written by scan)
//   csr_src  [E]     int       (written by fill)
//   dinv     [n]     float     (written by scan)
//   flag     [1]     int       (1 if edge_index is int64)
// ---------------------------------------------------------------------------

__global__ void detect_i64_kernel(const unsigned* __restrict__ e32, int* __restrict__ flag) {
    // int64 indices < 2^31: every odd 32-bit word is 0. For int32 random
    // indices the probability all 64 sampled odd words are 0 is ~0.
    int t = threadIdx.x;  // 64 threads
    unsigned v = e32[2 * t + 1];
    unsigned long long b = __ballot(v == 0u);
    if (t == 0) *flag = (b == ~0ULL) ? 1 : 0;
}

__global__ void zero_kernel(int* __restrict__ p, int count) {
    int i = blockIdx.x * 256 + threadIdx.x;
    int stride = gridDim.x * 256;
    for (; i < count; i += stride) p[i] = 0;
}

__global__ void deg_kernel(const void* __restrict__ eidx, const int* __restrict__ flag,
                           int* __restrict__ deg_i, int E) {
    int e = blockIdx.x * 256 + threadIdx.x;
    if (e >= E) return;
    int dst;
    if (*flag) dst = (int)((const long long*)eidx)[(long long)E + e];
    else       dst = ((const int*)eidx)[E + e];
    atomicAdd(&deg_i[dst], 1);
}

// Single-block exclusive scan over deg_i[n] -> row_start[n+1], cursor[n];
// also emits dinv[i] = rsqrt(deg+1).
__global__ __launch_bounds__(1024) void scan_kernel(const int* __restrict__ deg_i,
                                                    int* __restrict__ row_start,
                                                    int* __restrict__ cursor,
                                                    float* __restrict__ dinv, int n) {
    __shared__ int s[1024];
    int t = threadIdx.x;
    int chunk = (n + 1023) >> 10;
    int beg = t * chunk;
    int end = beg + chunk;
    if (beg > n) beg = n;
    if (end > n) end = n;

    int lsum = 0;
    for (int i = beg; i < end; ++i) lsum += deg_i[i];
    s[t] = lsum;
    __syncthreads();
    // inclusive scan of the 1024 partials
    for (int off = 1; off < 1024; off <<= 1) {
        int v = (t >= off) ? s[t - off] : 0;
        __syncthreads();
        s[t] += v;
        __syncthreads();
    }
    int base = s[t] - lsum;  // exclusive prefix for this thread's chunk
    int run = base;
    for (int i = beg; i < end; ++i) {
        int d = deg_i[i];
        row_start[i] = run;
        cursor[i] = run;
        dinv[i] = rsqrtf((float)d + 1.0f);  // +1 self-loop
        run += d;
    }
    if (t == 1023) row_start[n] = s[1023];
}

__global__ void fill_kernel(const void* __restrict__ eidx, const int* __restrict__ flag,
                            int* __restrict__ cursor, int* __restrict__ csr_src, int E) {
    int e = blockIdx.x * 256 + threadIdx.x;
    if (e >= E) return;
    int src, dst;
    if (*flag) {
        const long long* p = (const long long*)eidx;
        src = (int)p[e];
        dst = (int)p[(long long)E + e];
    } else {
        const int* p = (const int*)eidx;
        src = p[e];
        dst = p[E + e];
    }
    int pos = atomicAdd(&cursor[dst], 1);
    csr_src[pos] = src;
}

// lin = x @ W.  W (128x128 fp32, 64KB) staged in LDS; 8 rows of x per chunk;
// each thread computes 1 column for 4 rows (W LDS read amortized 4x).
__global__ __launch_bounds__(256, 2) void gemm_kernel(const float* __restrict__ x,
                                                      const float* __restrict__ W,
                                                      float* __restrict__ lin, int n) {
    __shared__ float Ws[128 * 128];
    __shared__ float xs[8 * 128];
    int t = threadIdx.x;
    for (int i = t; i < 128 * 128; i += 256) Ws[i] = W[i];

    int c = t & 127;
    int g = t >> 7;  // 0/1 -> rows g*4 .. g*4+3 of the 8-row chunk
    int nchunk = (n + 7) >> 3;

    for (int ch = blockIdx.x; ch < nchunk; ch += gridDim.x) {
        int r0 = ch << 3;
        __syncthreads();  // also covers Ws store on first iteration
        for (int i = t; i < 1024; i += 256) {
            int r = r0 + (i >> 7);
            xs[i] = (r < n) ? x[(long long)r * 128 + (i & 127)] : 0.0f;
        }
        __syncthreads();

        const float4* xb0 = (const float4*)&xs[(g * 4 + 0) * 128];
        const float4* xb1 = (const float4*)&xs[(g * 4 + 1) * 128];
        const float4* xb2 = (const float4*)&xs[(g * 4 + 2) * 128];
        const float4* xb3 = (const float4*)&xs[(g * 4 + 3) * 128];
        float a0 = 0.f, a1 = 0.f, a2 = 0.f, a3 = 0.f;
#pragma unroll 8
        for (int k4 = 0; k4 < 32; ++k4) {
            float4 x0 = xb0[k4], x1 = xb1[k4], x2 = xb2[k4], x3 = xb3[k4];
            int kb = k4 * 4;
            float w0 = Ws[(kb + 0) * 128 + c];
            float w1 = Ws[(kb + 1) * 128 + c];
            float w2 = Ws[(kb + 2) * 128 + c];
            float w3 = Ws[(kb + 3) * 128 + c];
            a0 += x0.x * w0 + x0.y * w1 + x0.z * w2 + x0.w * w3;
            a1 += x1.x * w0 + x1.y * w1 + x1.z * w2 + x1.w * w3;
            a2 += x2.x * w0 + x2.y * w1 + x2.z * w2 + x2.w * w3;
            a3 += x3.x * w0 + x3.y * w1 + x3.z * w2 + x3.w * w3;
        }
        int r = r0 + g * 4;
        if (r + 3 < n) {
            lin[(long long)(r + 0) * 128 + c] = a0;
            lin[(long long)(r + 1) * 128 + c] = a1;
            lin[(long long)(r + 2) * 128 + c] = a2;
            lin[(long long)(r + 3) * 128 + c] = a3;
        } else {
            if (r + 0 < n) lin[(long long)(r + 0) * 128 + c] = a0;
            if (r + 1 < n) lin[(long long)(r + 1) * 128 + c] = a1;
            if (r + 2 < n) lin[(long long)(r + 2) * 128 + c] = a2;
            if (r + 3 < n) lin[(long long)(r + 3) * 128 + c] = a3;
        }
    }
}

// One 32-lane group per node: h[v] = sum_{s in N(v)} lin[s]*dinv[s]*dinv[v]
//                                  + lin[v]*dinv[v]^2 + b
// Also accumulates per-column sum / sumsq for BatchNorm (block-reduced).
__global__ __launch_bounds__(256) void gather_kernel(const int* __restrict__ row_start,
                                                     const int* __restrict__ csr_src,
                                                     const float* __restrict__ lin,
                                                     const float* __restrict__ dinv,
                                                     const float* __restrict__ b,
                                                     float* __restrict__ h,
                                                     float* __restrict__ colsum,
                                                     float* __restrict__ colsumsq, int n) {
    __shared__ float4 ssum[256];
    __shared__ float4 ssq[256];
    int t = threadIdx.x;
    int lane = t & 31;
    int grp = t >> 5;  // 8 groups of 32
    float4 bb = ((const float4*)b)[lane];
    float4 lsum = make_float4(0.f, 0.f, 0.f, 0.f);
    float4 lsq = make_float4(0.f, 0.f, 0.f, 0.f);

    for (int v = blockIdx.x * 8 + grp; v < n; v += gridDim.x * 8) {
        float dv = dinv[v];
        int beg = row_start[v];
        int end = row_start[v + 1];
        // self-loop term
        float4 acc = ((const float4*)(lin + (long long)v * 128))[lane];
        float dv2 = dv * dv;
        acc.x *= dv2; acc.y *= dv2; acc.z *= dv2; acc.w *= dv2;

        for (int jb = beg; jb < end; jb += 32) {
            int j = jb + lane;
            int idx = (j < end) ? csr_src[j] : 0;
            float dn = (j < end) ? dinv[idx] : 0.f;
            int m = end - jb;
            if (m > 32) m = 32;
            for (int k = 0; k < m; ++k) {
                int s = __shfl(idx, k, 32);
                float nrm = __shfl(dn, k, 32) * dv;
                float4 v4 = ((const float4*)(lin + (long long)s * 128))[lane];
                acc.x += v4.x * nrm;
                acc.y += v4.y * nrm;
                acc.z += v4.z * nrm;
                acc.w += v4.w * nrm;
            }
        }
        acc.x += bb.x; acc.y += bb.y; acc.z += bb.z; acc.w += bb.w;
        ((float4*)(h + (long long)v * 128))[lane] = acc;
        lsum.x += acc.x; lsum.y += acc.y; lsum.z += acc.z; lsum.w += acc.w;
        lsq.x += acc.x * acc.x; lsq.y += acc.y * acc.y;
        lsq.z += acc.z * acc.z; lsq.w += acc.w * acc.w;
    }

    ssum[t] = lsum;
    ssq[t] = lsq;
    __syncthreads();
    if (t < 32) {
        float4 a = ssum[t];
        float4 q = ssq[t];
        for (int g2 = 1; g2 < 8; ++g2) {
            float4 a2 = ssum[g2 * 32 + t];
            float4 q2 = ssq[g2 * 32 + t];
            a.x += a2.x; a.y += a2.y; a.z += a2.z; a.w += a2.w;
            q.x += q2.x; q.y += q2.y; q.z += q2.z; q.w += q2.w;
        }
        atomicAdd(&colsum[t * 4 + 0], a.x);
        atomicAdd(&colsum[t * 4 + 1], a.y);
        atomicAdd(&colsum[t * 4 + 2], a.z);
        atomicAdd(&colsum[t * 4 + 3], a.w);
        atomicAdd(&colsumsq[t * 4 + 0], q.x);
        atomicAdd(&colsumsq[t * 4 + 1], q.y);
        atomicAdd(&colsumsq[t * 4 + 2], q.z);
        atomicAdd(&colsumsq[t * 4 + 3], q.w);
    }
}

// out = relu((h-mean)*rsqrt(var+eps)*gamma + beta) + x    (float4 over columns)
__global__ __launch_bounds__(256) void out_kernel(const float* __restrict__ h,
                                                  const float* __restrict__ x,
                                                  const float* __restrict__ colsum,
                                                  const float* __restrict__ colsumsq,
                                                  const float* __restrict__ gamma,
                                                  const float* __restrict__ beta,
                                                  float* __restrict__ out, int n) {
    long long total4 = (long long)n * 32;
    long long i = (long long)blockIdx.x * 256 + threadIdx.x;
    long long stride = (long long)gridDim.x * 256;
    float inv_n = 1.0f / (float)n;
    for (; i < total4; i += stride) {
        int c4 = (int)(i & 31);
        float4 cs = ((const float4*)colsum)[c4];
        float4 cq = ((const float4*)colsumsq)[c4];
        float4 g = ((const float4*)gamma)[c4];
        float4 bt = ((const float4*)beta)[c4];
        float4 hv = ((const float4*)h)[i];
        float4 xv = ((const float4*)x)[i];
        float m0 = cs.x * inv_n, m1 = cs.y * inv_n, m2 = cs.z * inv_n, m3 = cs.w * inv_n;
        float r0 = rsqrtf(cq.x * inv_n - m0 * m0 + BN_EPS);
        float r1 = rsqrtf(cq.y * inv_n - m1 * m1 + BN_EPS);
        float r2 = rsqrtf(cq.z * inv_n - m2 * m2 + BN_EPS);
        float r3 = rsqrtf(cq.w * inv_n - m3 * m3 + BN_EPS);
        float4 o;
        o.x = fmaxf((hv.x - m0) * r0 * g.x + bt.x, 0.f) + xv.x;
        o.y = fmaxf((hv.y - m1) * r1 * g.y + bt.y, 0.f) + xv.y;
        o.z = fmaxf((hv.z - m2) * r2 * g.z + bt.z, 0.f) + xv.z;
        o.w = fmaxf((hv.w - m3) * r3 * g.w + bt.w, 0.f) + xv.w;
        ((float4*)out)[i] = o;
    }
}

extern "C" void kernel_launch(void* const* d_in, const int* in_sizes, int n_in,
                              void* d_out, int out_size, void* d_ws, size_t ws_size,
                              hipStream_t stream) {
    const float* x     = (const float*)d_in[0];
    const void*  eidx  = d_in[1];
    const float* W     = (const float*)d_in[2];
    const float* b     = (const float*)d_in[3];
    const float* gamma = (const float*)d_in[4];
    const float* beta  = (const float*)d_in[5];
    float* out = (float*)d_out;

    int n = in_sizes[0] / 128;
    int E = in_sizes[1] / 2;

    float* ws = (float*)d_ws;
    long long nd = (long long)n * 128;
    float* lin       = ws;
    float* h         = ws + nd;
    int*   deg_i     = (int*)(ws + 2 * nd);
    float* colsum    = (float*)(deg_i + n);
    float* colsumsq  = colsum + 128;
    int*   row_start = (int*)(colsumsq + 128);
    int*   cursor    = row_start + (n + 1);
    int*   csr_src   = cursor + n;
    float* dinv      = (float*)(csr_src + E);
    int*   flag      = (int*)(dinv + n);

    detect_i64_kernel<<<1, 64, 0, stream>>>((const unsigned*)eidx, flag);

    // zero deg_i + colsum + colsumsq (contiguous)
    zero_kernel<<<512, 256, 0, stream>>>(deg_i, n + 256);

    deg_kernel<<<(E + 255) / 256, 256, 0, stream>>>(eidx, flag, deg_i, E);
    scan_kernel<<<1, 1024, 0, stream>>>(deg_i, row_start, cursor, dinv, n);
    fill_kernel<<<(E + 255) / 256, 256, 0, stream>>>(eidx, flag, cursor, csr_src, E);

    gemm_kernel<<<512, 256, 0, stream>>>(x, W, lin, n);

    gather_kernel<<<1280, 256, 0, stream>>>(row_start, csr_src, lin, dinv, b, h,
                                            colsum, colsumsq, n);

    out_kernel<<<2048, 256, 0, stream>>>(h, x, colsum, colsumsq, gamma, beta, out, n);
}

// Round 3
// 379.922 us; speedup vs baseline: 1.3540x; 1.3540x over previous
//
#include <hip/hip_runtime.h>

#define BN_EPS 1e-5f

// ---------------------------------------------------------------------------
// ws layout (4-byte elements):
//   lin      [n*128] float     (x @ W)
//   h        [n*128] float     (pre-BN activations)
//   deg_i    [n]     int       (zeroed)
//   colsum   [128]   float     (zeroed)
//   colsumsq [128]   float     (zeroed)
//   row_start[n+1]   int       (CSR offsets)
//   cursor   [n]     int
//   csr_src  [E]     int
//   dinv     [n]     float
//   flag     [1]     int       (1 if edge_index is int64)
//   bsum     [1024]  int       (scan block partials)
// ---------------------------------------------------------------------------

__global__ void detect_i64_kernel(const unsigned* __restrict__ e32, int* __restrict__ flag) {
    // int64 indices < 2^31: every odd 32-bit word is 0. For int32 random
    // indices the probability all 64 sampled odd words are 0 is ~0.
    int t = threadIdx.x;  // 64 threads
    unsigned v = e32[2 * t + 1];
    unsigned long long b = __ballot(v == 0u);
    if (t == 0) *flag = (b == ~0ULL) ? 1 : 0;
}

__global__ void zero_kernel(int* __restrict__ p, int count) {
    int i = blockIdx.x * 256 + threadIdx.x;
    int stride = gridDim.x * 256;
    for (; i < count; i += stride) p[i] = 0;
}

__global__ void deg_kernel(const void* __restrict__ eidx, const int* __restrict__ flag,
                           int* __restrict__ deg_i, int E) {
    int e = blockIdx.x * 256 + threadIdx.x;
    if (e >= E) return;
    int dst;
    if (*flag) dst = (int)((const long long*)eidx)[(long long)E + e];
    else       dst = ((const int*)eidx)[E + e];
    atomicAdd(&deg_i[dst], 1);
}

// ---- 3-phase exclusive scan over deg_i[n] (1024 elements per block) ----
__global__ __launch_bounds__(256) void scan1_kernel(const int* __restrict__ deg_i,
                                                    int* __restrict__ bsum, int n) {
    __shared__ int s[256];
    int t = threadIdx.x;
    int base = blockIdx.x * 1024 + t * 4;
    int v = 0;
    if (base + 3 < n) {
        int4 d = *(const int4*)(deg_i + base);
        v = d.x + d.y + d.z + d.w;
    } else {
        for (int i = 0; i < 4; ++i) if (base + i < n) v += deg_i[base + i];
    }
    s[t] = v;
    __syncthreads();
    for (int off = 128; off > 0; off >>= 1) {
        if (t < off) s[t] += s[t + off];
        __syncthreads();
    }
    if (t == 0) bsum[blockIdx.x] = s[0];
}

// single block: exclusive-scan bsum[nb] (nb <= 1024); also row_start[n] = E
__global__ __launch_bounds__(1024) void scan2_kernel(int* __restrict__ bsum, int nb,
                                                     int* __restrict__ row_start,
                                                     int n, int E) {
    __shared__ int s[1024];
    int t = threadIdx.x;
    int v = (t < nb) ? bsum[t] : 0;
    s[t] = v;
    __syncthreads();
    for (int off = 1; off < 1024; off <<= 1) {
        int u = (t >= off) ? s[t - off] : 0;
        __syncthreads();
        s[t] += u;
        __syncthreads();
    }
    if (t < nb) bsum[t] = s[t] - v;  // exclusive
    if (t == 0) row_start[n] = E;
}

__global__ __launch_bounds__(256) void scan3_kernel(const int* __restrict__ deg_i,
                                                    const int* __restrict__ bsum,
                                                    int* __restrict__ row_start,
                                                    int* __restrict__ cursor,
                                                    float* __restrict__ dinv, int n) {
    __shared__ int s[256];
    int t = threadIdx.x;
    int base = blockIdx.x * 1024 + t * 4;
    int d0 = 0, d1 = 0, d2 = 0, d3 = 0;
    if (base + 3 < n) {
        int4 d = *(const int4*)(deg_i + base);
        d0 = d.x; d1 = d.y; d2 = d.z; d3 = d.w;
    } else {
        if (base + 0 < n) d0 = deg_i[base + 0];
        if (base + 1 < n) d1 = deg_i[base + 1];
        if (base + 2 < n) d2 = deg_i[base + 2];
        if (base + 3 < n) d3 = deg_i[base + 3];
    }
    int tsum = d0 + d1 + d2 + d3;
    s[t] = tsum;
    __syncthreads();
    for (int off = 1; off < 256; off <<= 1) {
        int u = (t >= off) ? s[t - off] : 0;
        __syncthreads();
        s[t] += u;
        __syncthreads();
    }
    int run = s[t] - tsum + bsum[blockIdx.x];
    int d[4] = {d0, d1, d2, d3};
    for (int i = 0; i < 4; ++i) {
        int idx = base + i;
        if (idx < n) {
            row_start[idx] = run;
            cursor[idx] = run;
            dinv[idx] = rsqrtf((float)d[i] + 1.0f);  // +1 self-loop
            run += d[i];
        }
    }
}

__global__ void fill_kernel(const void* __restrict__ eidx, const int* __restrict__ flag,
                            int* __restrict__ cursor, int* __restrict__ csr_src, int E) {
    int e = blockIdx.x * 256 + threadIdx.x;
    if (e >= E) return;
    int src, dst;
    if (*flag) {
        const long long* p = (const long long*)eidx;
        src = (int)p[e];
        dst = (int)p[(long long)E + e];
    } else {
        const int* p = (const int*)eidx;
        src = p[e];
        dst = p[E + e];
    }
    int pos = atomicAdd(&cursor[dst], 1);
    csr_src[pos] = src;
}

// lin = x @ W. W (64KB) + 32-row x tile (16KB) in LDS.
// Thread (c4 = t&31, rg = t>>5): 4 rows (rg*4..+3) x 4 cols (c4*4..+3).
// Per k4 step: 8 x ds_read_b128 -> 64 FMA  (~1.5 B LDS / FMA).
__global__ __launch_bounds__(256, 2) void gemm_kernel(const float* __restrict__ x,
                                                      const float* __restrict__ W,
                                                      float* __restrict__ lin, int n) {
    __shared__ float Ws[128 * 128];
    __shared__ float xs[32 * 128];
    int t = threadIdx.x;
    for (int i = t; i < 4096; i += 256) ((float4*)Ws)[i] = ((const float4*)W)[i];

    int c4 = t & 31;
    int rg = t >> 5;
    int nchunk = (n + 31) >> 5;

    for (int ch = blockIdx.x; ch < nchunk; ch += gridDim.x) {
        int r0 = ch << 5;
        __syncthreads();  // also covers Ws staging on first iteration
        for (int i = t; i < 1024; i += 256) {
            int r = r0 + (i >> 5);
            ((float4*)xs)[i] = (r < n) ? ((const float4*)x)[(long long)r * 32 + (i & 31)]
                                       : make_float4(0.f, 0.f, 0.f, 0.f);
        }
        __syncthreads();

        const float4* xr0 = (const float4*)(xs + (rg * 4 + 0) * 128);
        const float4* xr1 = (const float4*)(xs + (rg * 4 + 1) * 128);
        const float4* xr2 = (const float4*)(xs + (rg * 4 + 2) * 128);
        const float4* xr3 = (const float4*)(xs + (rg * 4 + 3) * 128);
        float4 a0 = make_float4(0.f, 0.f, 0.f, 0.f);
        float4 a1 = a0, a2 = a0, a3 = a0;

        for (int k4 = 0; k4 < 32; ++k4) {
            float4 xv0 = xr0[k4];
            float4 xv1 = xr1[k4];
            float4 xv2 = xr2[k4];
            float4 xv3 = xr3[k4];
            int kb = k4 * 4;
            float4 w0 = ((const float4*)(Ws + (kb + 0) * 128))[c4];
            float4 w1 = ((const float4*)(Ws + (kb + 1) * 128))[c4];
            float4 w2 = ((const float4*)(Ws + (kb + 2) * 128))[c4];
            float4 w3 = ((const float4*)(Ws + (kb + 3) * 128))[c4];
#define ACC(A, XV)                                                          \
            A.x += XV.x * w0.x + XV.y * w1.x + XV.z * w2.x + XV.w * w3.x;   \
            A.y += XV.x * w0.y + XV.y * w1.y + XV.z * w2.y + XV.w * w3.y;   \
            A.z += XV.x * w0.z + XV.y * w1.z + XV.z * w2.z + XV.w * w3.z;   \
            A.w += XV.x * w0.w + XV.y * w1.w + XV.z * w2.w + XV.w * w3.w
            ACC(a0, xv0);
            ACC(a1, xv1);
            ACC(a2, xv2);
            ACC(a3, xv3);
#undef ACC
        }
        int r = r0 + rg * 4;
        if (r + 3 < n) {
            ((float4*)(lin + (long long)(r + 0) * 128))[c4] = a0;
            ((float4*)(lin + (long long)(r + 1) * 128))[c4] = a1;
            ((float4*)(lin + (long long)(r + 2) * 128))[c4] = a2;
            ((float4*)(lin + (long long)(r + 3) * 128))[c4] = a3;
        } else {
            if (r + 0 < n) ((float4*)(lin + (long long)(r + 0) * 128))[c4] = a0;
            if (r + 1 < n) ((float4*)(lin + (long long)(r + 1) * 128))[c4] = a1;
            if (r + 2 < n) ((float4*)(lin + (long long)(r + 2) * 128))[c4] = a2;
            if (r + 3 < n) ((float4*)(lin + (long long)(r + 3) * 128))[c4] = a3;
        }
    }
}

// One 32-lane group per node; 8-deep unrolled edge loop for MLP.
__global__ __launch_bounds__(256) void gather_kernel(const int* __restrict__ row_start,
                                                     const int* __restrict__ csr_src,
                                                     const float* __restrict__ lin,
                                                     const float* __restrict__ dinv,
                                                     const float* __restrict__ b,
                                                     float* __restrict__ h,
                                                     float* __restrict__ colsum,
                                                     float* __restrict__ colsumsq, int n) {
    __shared__ float4 ssum[256];
    __shared__ float4 ssq[256];
    int t = threadIdx.x;
    int lane = t & 31;
    int grp = t >> 5;  // 8 groups of 32
    float4 bb = ((const float4*)b)[lane];
    float4 lsum = make_float4(0.f, 0.f, 0.f, 0.f);
    float4 lsq = make_float4(0.f, 0.f, 0.f, 0.f);

    for (int v = blockIdx.x * 8 + grp; v < n; v += gridDim.x * 8) {
        float dv = dinv[v];
        int beg = row_start[v];
        int end = row_start[v + 1];
        float4 acc = ((const float4*)(lin + (long long)v * 128))[lane];
        float dv2 = dv * dv;
        acc.x *= dv2; acc.y *= dv2; acc.z *= dv2; acc.w *= dv2;

        for (int jb = beg; jb < end; jb += 32) {
            int j = jb + lane;
            int idx = (j < end) ? csr_src[j] : 0;
            float dn = (j < end) ? dinv[idx] * dv : 0.f;  // premultiplied norm
            int m = end - jb;
            if (m > 32) m = 32;
            int k = 0;
            for (; k + 8 <= m; k += 8) {
                int s0 = __shfl(idx, k + 0, 32); float n0 = __shfl(dn, k + 0, 32);
                int s1 = __shfl(idx, k + 1, 32); float n1 = __shfl(dn, k + 1, 32);
                int s2 = __shfl(idx, k + 2, 32); float n2 = __shfl(dn, k + 2, 32);
                int s3 = __shfl(idx, k + 3, 32); float n3 = __shfl(dn, k + 3, 32);
                int s4 = __shfl(idx, k + 4, 32); float n4 = __shfl(dn, k + 4, 32);
                int s5 = __shfl(idx, k + 5, 32); float n5 = __shfl(dn, k + 5, 32);
                int s6 = __shfl(idx, k + 6, 32); float n6 = __shfl(dn, k + 6, 32);
                int s7 = __shfl(idx, k + 7, 32); float n7 = __shfl(dn, k + 7, 32);
                float4 v0 = ((const float4*)(lin + (long long)s0 * 128))[lane];
                float4 v1 = ((const float4*)(lin + (long long)s1 * 128))[lane];
                float4 v2 = ((const float4*)(lin + (long long)s2 * 128))[lane];
                float4 v3 = ((const float4*)(lin + (long long)s3 * 128))[lane];
                float4 v4 = ((const float4*)(lin + (long long)s4 * 128))[lane];
                float4 v5 = ((const float4*)(lin + (long long)s5 * 128))[lane];
                float4 v6 = ((const float4*)(lin + (long long)s6 * 128))[lane];
                float4 v7 = ((const float4*)(lin + (long long)s7 * 128))[lane];
                acc.x += v0.x * n0 + v1.x * n1 + v2.x * n2 + v3.x * n3
                       + v4.x * n4 + v5.x * n5 + v6.x * n6 + v7.x * n7;
                acc.y += v0.y * n0 + v1.y * n1 + v2.y * n2 + v3.y * n3
                       + v4.y * n4 + v5.y * n5 + v6.y * n6 + v7.y * n7;
                acc.z += v0.z * n0 + v1.z * n1 + v2.z * n2 + v3.z * n3
                       + v4.z * n4 + v5.z * n5 + v6.z * n6 + v7.z * n7;
                acc.w += v0.w * n0 + v1.w * n1 + v2.w * n2 + v3.w * n3
                       + v4.w * n4 + v5.w * n5 + v6.w * n6 + v7.w * n7;
            }
            for (; k + 4 <= m; k += 4) {
                int s0 = __shfl(idx, k + 0, 32); float n0 = __shfl(dn, k + 0, 32);
                int s1 = __shfl(idx, k + 1, 32); float n1 = __shfl(dn, k + 1, 32);
                int s2 = __shfl(idx, k + 2, 32); float n2 = __shfl(dn, k + 2, 32);
                int s3 = __shfl(idx, k + 3, 32); float n3 = __shfl(dn, k + 3, 32);
                float4 v0 = ((const float4*)(lin + (long long)s0 * 128))[lane];
                float4 v1 = ((const float4*)(lin + (long long)s1 * 128))[lane];
                float4 v2 = ((const float4*)(lin + (long long)s2 * 128))[lane];
                float4 v3 = ((const float4*)(lin + (long long)s3 * 128))[lane];
                acc.x += v0.x * n0 + v1.x * n1 + v2.x * n2 + v3.x * n3;
                acc.y += v0.y * n0 + v1.y * n1 + v2.y * n2 + v3.y * n3;
                acc.z += v0.z * n0 + v1.z * n1 + v2.z * n2 + v3.z * n3;
                acc.w += v0.w * n0 + v1.w * n1 + v2.w * n2 + v3.w * n3;
            }
            for (; k < m; ++k) {
                int s0 = __shfl(idx, k, 32);
                float n0 = __shfl(dn, k, 32);
                float4 v0 = ((const float4*)(lin + (long long)s0 * 128))[lane];
                acc.x += v0.x * n0;
                acc.y += v0.y * n0;
                acc.z += v0.z * n0;
                acc.w += v0.w * n0;
            }
        }
        acc.x += bb.x; acc.y += bb.y; acc.z += bb.z; acc.w += bb.w;
        ((float4*)(h + (long long)v * 128))[lane] = acc;
        lsum.x += acc.x; lsum.y += acc.y; lsum.z += acc.z; lsum.w += acc.w;
        lsq.x += acc.x * acc.x; lsq.y += acc.y * acc.y;
        lsq.z += acc.z * acc.z; lsq.w += acc.w * acc.w;
    }

    ssum[t] = lsum;
    ssq[t] = lsq;
    __syncthreads();
    if (t < 32) {
        float4 a = ssum[t];
        float4 q = ssq[t];
        for (int g2 = 1; g2 < 8; ++g2) {
            float4 a2 = ssum[g2 * 32 + t];
            float4 q2 = ssq[g2 * 32 + t];
            a.x += a2.x; a.y += a2.y; a.z += a2.z; a.w += a2.w;
            q.x += q2.x; q.y += q2.y; q.z += q2.z; q.w += q2.w;
        }
        atomicAdd(&colsum[t * 4 + 0], a.x);
        atomicAdd(&colsum[t * 4 + 1], a.y);
        atomicAdd(&colsum[t * 4 + 2], a.z);
        atomicAdd(&colsum[t * 4 + 3], a.w);
        atomicAdd(&colsumsq[t * 4 + 0], q.x);
        atomicAdd(&colsumsq[t * 4 + 1], q.y);
        atomicAdd(&colsumsq[t * 4 + 2], q.z);
        atomicAdd(&colsumsq[t * 4 + 3], q.w);
    }
}

// out = relu((h-mean)*rsqrt(var+eps)*gamma + beta) + x    (float4 over columns)
__global__ __launch_bounds__(256) void out_kernel(const float* __restrict__ h,
                                                  const float* __restrict__ x,
                                                  const float* __restrict__ colsum,
                                                  const float* __restrict__ colsumsq,
                                                  const float* __restrict__ gamma,
                                                  const float* __restrict__ beta,
                                                  float* __restrict__ out, int n) {
    long long total4 = (long long)n * 32;
    long long i = (long long)blockIdx.x * 256 + threadIdx.x;
    long long stride = (long long)gridDim.x * 256;
    float inv_n = 1.0f / (float)n;
    for (; i < total4; i += stride) {
        int c4 = (int)(i & 31);
        float4 cs = ((const float4*)colsum)[c4];
        float4 cq = ((const float4*)colsumsq)[c4];
        float4 g = ((const float4*)gamma)[c4];
        float4 bt = ((const float4*)beta)[c4];
        float4 hv = ((const float4*)h)[i];
        float4 xv = ((const float4*)x)[i];
        float m0 = cs.x * inv_n, m1 = cs.y * inv_n, m2 = cs.z * inv_n, m3 = cs.w * inv_n;
        float r0 = rsqrtf(cq.x * inv_n - m0 * m0 + BN_EPS);
        float r1 = rsqrtf(cq.y * inv_n - m1 * m1 + BN_EPS);
        float r2 = rsqrtf(cq.z * inv_n - m2 * m2 + BN_EPS);
        float r3 = rsqrtf(cq.w * inv_n - m3 * m3 + BN_EPS);
        float4 o;
        o.x = fmaxf((hv.x - m0) * r0 * g.x + bt.x, 0.f) + xv.x;
        o.y = fmaxf((hv.y - m1) * r1 * g.y + bt.y, 0.f) + xv.y;
        o.z = fmaxf((hv.z - m2) * r2 * g.z + bt.z, 0.f) + xv.z;
        o.w = fmaxf((hv.w - m3) * r3 * g.w + bt.w, 0.f) + xv.w;
        ((float4*)out)[i] = o;
    }
}

extern "C" void kernel_launch(void* const* d_in, const int* in_sizes, int n_in,
                              void* d_out, int out_size, void* d_ws, size_t ws_size,
                              hipStream_t stream) {
    const float* x     = (const float*)d_in[0];
    const void*  eidx  = d_in[1];
    const float* W     = (const float*)d_in[2];
    const float* b     = (const float*)d_in[3];
    const float* gamma = (const float*)d_in[4];
    const float* beta  = (const float*)d_in[5];
    float* out = (float*)d_out;

    int n = in_sizes[0] / 128;
    int E = in_sizes[1] / 2;

    float* ws = (float*)d_ws;
    long long nd = (long long)n * 128;
    float* lin       = ws;
    float* h         = ws + nd;
    int*   deg_i     = (int*)(ws + 2 * nd);
    float* colsum    = (float*)(deg_i + n);
    float* colsumsq  = colsum + 128;
    int*   row_start = (int*)(colsumsq + 128);
    int*   cursor    = row_start + (n + 1);
    int*   csr_src   = cursor + n;
    float* dinv      = (float*)(csr_src + E);
    int*   flag      = (int*)(dinv + n);
    int*   bsum      = flag + 1;

    detect_i64_kernel<<<1, 64, 0, stream>>>((const unsigned*)eidx, flag);

    // zero deg_i + colsum + colsumsq (contiguous)
    zero_kernel<<<512, 256, 0, stream>>>(deg_i, n + 256);

    deg_kernel<<<(E + 255) / 256, 256, 0, stream>>>(eidx, flag, deg_i, E);

    int nb = (n + 1023) / 1024;
    scan1_kernel<<<nb, 256, 0, stream>>>(deg_i, bsum, n);
    scan2_kernel<<<1, 1024, 0, stream>>>(bsum, nb, row_start, n, E);
    scan3_kernel<<<nb, 256, 0, stream>>>(deg_i, bsum, row_start, cursor, dinv, n);

    fill_kernel<<<(E + 255) / 256, 256, 0, stream>>>(eidx, flag, cursor, csr_src, E);

    gemm_kernel<<<512, 256, 0, stream>>>(x, W, lin, n);

    gather_kernel<<<1568, 256, 0, stream>>>(row_start, csr_src, lin, dinv, b, h,
                                            colsum, colsumsq, n);

    out_kernel<<<2048, 256, 0, stream>>>(h, x, colsum, colsumsq, gamma, beta, out, n);
}

// Round 4
// 274.809 us; speedup vs baseline: 1.8719x; 1.3825x over previous
//
#include <hip/hip_runtime.h>

#define BN_EPS 1e-5f

// ---------------------------------------------------------------------------
// ws layout (4-byte elements):
//   lin      [n*128] float     (x @ W)
//   h        [n*128] float     (pre-BN activations)
//   deg_i    [n]     int       (zeroed)
//   colsum   [128]   float     (zeroed)
//   colsumsq [128]   float     (zeroed)
//   row_start[n+1]   int       (CSR offsets)
//   cursor   [n]     int
//   csr_src  [E]     int
//   dinv     [n]     float
//   flag     [1]     int       (1 if edge_index is int64)
//   bsum     [1024]  int       (scan block partials)
// ---------------------------------------------------------------------------

__global__ void detect_i64_kernel(const unsigned* __restrict__ e32, int* __restrict__ flag) {
    // int64 indices < 2^31: every odd 32-bit word is 0. For int32 random
    // indices the probability all 64 sampled odd words are 0 is ~0.
    int t = threadIdx.x;  // 64 threads
    unsigned v = e32[2 * t + 1];
    unsigned long long b = __ballot(v == 0u);
    if (t == 0) *flag = (b == ~0ULL) ? 1 : 0;
}

__global__ void zero_kernel(int* __restrict__ p, int count) {
    int i = blockIdx.x * 256 + threadIdx.x;
    int stride = gridDim.x * 256;
    for (; i < count; i += stride) p[i] = 0;
}

__global__ void deg_kernel(const void* __restrict__ eidx, const int* __restrict__ flag,
                           int* __restrict__ deg_i, int E) {
    int e = blockIdx.x * 256 + threadIdx.x;
    if (e >= E) return;
    int dst;
    if (*flag) dst = (int)((const long long*)eidx)[(long long)E + e];
    else       dst = ((const int*)eidx)[E + e];
    atomicAdd(&deg_i[dst], 1);
}

// ---- 3-phase exclusive scan over deg_i[n] (1024 elements per block) ----
__global__ __launch_bounds__(256) void scan1_kernel(const int* __restrict__ deg_i,
                                                    int* __restrict__ bsum, int n) {
    __shared__ int s[256];
    int t = threadIdx.x;
    int base = blockIdx.x * 1024 + t * 4;
    int v = 0;
    if (base + 3 < n) {
        int4 d = *(const int4*)(deg_i + base);
        v = d.x + d.y + d.z + d.w;
    } else {
        for (int i = 0; i < 4; ++i) if (base + i < n) v += deg_i[base + i];
    }
    s[t] = v;
    __syncthreads();
    for (int off = 128; off > 0; off >>= 1) {
        if (t < off) s[t] += s[t + off];
        __syncthreads();
    }
    if (t == 0) bsum[blockIdx.x] = s[0];
}

// single block: exclusive-scan bsum[nb] (nb <= 1024); also row_start[n] = E
__global__ __launch_bounds__(1024) void scan2_kernel(int* __restrict__ bsum, int nb,
                                                     int* __restrict__ row_start,
                                                     int n, int E) {
    __shared__ int s[1024];
    int t = threadIdx.x;
    int v = (t < nb) ? bsum[t] : 0;
    s[t] = v;
    __syncthreads();
    for (int off = 1; off < 1024; off <<= 1) {
        int u = (t >= off) ? s[t - off] : 0;
        __syncthreads();
        s[t] += u;
        __syncthreads();
    }
    if (t < nb) bsum[t] = s[t] - v;  // exclusive
    if (t == 0) row_start[n] = E;
}

__global__ __launch_bounds__(256) void scan3_kernel(const int* __restrict__ deg_i,
                                                    const int* __restrict__ bsum,
                                                    int* __restrict__ row_start,
                                                    int* __restrict__ cursor,
                                                    float* __restrict__ dinv, int n) {
    __shared__ int s[256];
    int t = threadIdx.x;
    int base = blockIdx.x * 1024 + t * 4;
    int d0 = 0, d1 = 0, d2 = 0, d3 = 0;
    if (base + 3 < n) {
        int4 d = *(const int4*)(deg_i + base);
        d0 = d.x; d1 = d.y; d2 = d.z; d3 = d.w;
    } else {
        if (base + 0 < n) d0 = deg_i[base + 0];
        if (base + 1 < n) d1 = deg_i[base + 1];
        if (base + 2 < n) d2 = deg_i[base + 2];
        if (base + 3 < n) d3 = deg_i[base + 3];
    }
    int tsum = d0 + d1 + d2 + d3;
    s[t] = tsum;
    __syncthreads();
    for (int off = 1; off < 256; off <<= 1) {
        int u = (t >= off) ? s[t - off] : 0;
        __syncthreads();
        s[t] += u;
        __syncthreads();
    }
    int run = s[t] - tsum + bsum[blockIdx.x];
    int d[4] = {d0, d1, d2, d3};
    for (int i = 0; i < 4; ++i) {
        int idx = base + i;
        if (idx < n) {
            row_start[idx] = run;
            cursor[idx] = run;
            dinv[idx] = rsqrtf((float)d[i] + 1.0f);  // +1 self-loop
            run += d[i];
        }
    }
}

__global__ void fill_kernel(const void* __restrict__ eidx, const int* __restrict__ flag,
                            int* __restrict__ cursor, int* __restrict__ csr_src, int E) {
    int e = blockIdx.x * 256 + threadIdx.x;
    if (e >= E) return;
    int src, dst;
    if (*flag) {
        const long long* p = (const long long*)eidx;
        src = (int)p[e];
        dst = (int)p[(long long)E + e];
    } else {
        const int* p = (const int*)eidx;
        src = p[e];
        dst = p[E + e];
    }
    int pos = atomicAdd(&cursor[dst], 1);
    csr_src[pos] = src;
}

// lin = x @ W. W (64KB) + 32-row x tile (16KB) in LDS.
// Thread (c4 = t&31, rg = t>>5): 4 rows (rg*4..+3) x 4 cols (c4*4..+3).
// Per k4 step: 8 x ds_read_b128 -> 64 FMA  (~1.5 B LDS / FMA).
__global__ __launch_bounds__(256, 2) void gemm_kernel(const float* __restrict__ x,
                                                      const float* __restrict__ W,
                                                      float* __restrict__ lin, int n) {
    __shared__ float Ws[128 * 128];
    __shared__ float xs[32 * 128];
    int t = threadIdx.x;
    for (int i = t; i < 4096; i += 256) ((float4*)Ws)[i] = ((const float4*)W)[i];

    int c4 = t & 31;
    int rg = t >> 5;
    int nchunk = (n + 31) >> 5;

    for (int ch = blockIdx.x; ch < nchunk; ch += gridDim.x) {
        int r0 = ch << 5;
        __syncthreads();  // also covers Ws staging on first iteration
        for (int i = t; i < 1024; i += 256) {
            int r = r0 + (i >> 5);
            ((float4*)xs)[i] = (r < n) ? ((const float4*)x)[(long long)r * 32 + (i & 31)]
                                       : make_float4(0.f, 0.f, 0.f, 0.f);
        }
        __syncthreads();

        const float4* xr0 = (const float4*)(xs + (rg * 4 + 0) * 128);
        const float4* xr1 = (const float4*)(xs + (rg * 4 + 1) * 128);
        const float4* xr2 = (const float4*)(xs + (rg * 4 + 2) * 128);
        const float4* xr3 = (const float4*)(xs + (rg * 4 + 3) * 128);
        float4 a0 = make_float4(0.f, 0.f, 0.f, 0.f);
        float4 a1 = a0, a2 = a0, a3 = a0;

        for (int k4 = 0; k4 < 32; ++k4) {
            float4 xv0 = xr0[k4];
            float4 xv1 = xr1[k4];
            float4 xv2 = xr2[k4];
            float4 xv3 = xr3[k4];
            int kb = k4 * 4;
            float4 w0 = ((const float4*)(Ws + (kb + 0) * 128))[c4];
            float4 w1 = ((const float4*)(Ws + (kb + 1) * 128))[c4];
            float4 w2 = ((const float4*)(Ws + (kb + 2) * 128))[c4];
            float4 w3 = ((const float4*)(Ws + (kb + 3) * 128))[c4];
#define ACC(A, XV)                                                          \
            A.x += XV.x * w0.x + XV.y * w1.x + XV.z * w2.x + XV.w * w3.x;   \
            A.y += XV.x * w0.y + XV.y * w1.y + XV.z * w2.y + XV.w * w3.y;   \
            A.z += XV.x * w0.z + XV.y * w1.z + XV.z * w2.z + XV.w * w3.z;   \
            A.w += XV.x * w0.w + XV.y * w1.w + XV.z * w2.w + XV.w * w3.w
            ACC(a0, xv0);
            ACC(a1, xv1);
            ACC(a2, xv2);
            ACC(a3, xv3);
#undef ACC
        }
        int r = r0 + rg * 4;
        if (r + 3 < n) {
            ((float4*)(lin + (long long)(r + 0) * 128))[c4] = a0;
            ((float4*)(lin + (long long)(r + 1) * 128))[c4] = a1;
            ((float4*)(lin + (long long)(r + 2) * 128))[c4] = a2;
            ((float4*)(lin + (long long)(r + 3) * 128))[c4] = a3;
        } else {
            if (r + 0 < n) ((float4*)(lin + (long long)(r + 0) * 128))[c4] = a0;
            if (r + 1 < n) ((float4*)(lin + (long long)(r + 1) * 128))[c4] = a1;
            if (r + 2 < n) ((float4*)(lin + (long long)(r + 2) * 128))[c4] = a2;
            if (r + 3 < n) ((float4*)(lin + (long long)(r + 3) * 128))[c4] = a3;
        }
    }
}

// One 32-lane group per node, one node per group (no loop, no LDS, no atomics):
// h[v] = sum_{s in N(v)} lin[s]*dinv[s]*dinv[v] + lin[v]*dinv[v]^2 + b
__global__ __launch_bounds__(256) void gather_kernel(const int* __restrict__ row_start,
                                                     const int* __restrict__ csr_src,
                                                     const float* __restrict__ lin,
                                                     const float* __restrict__ dinv,
                                                     const float* __restrict__ b,
                                                     float* __restrict__ h, int n) {
    int t = threadIdx.x;
    int lane = t & 31;
    int grp = t >> 5;  // 8 groups of 32
    int v = blockIdx.x * 8 + grp;
    if (v >= n) return;

    float dv = dinv[v];
    int beg = row_start[v];
    int end = row_start[v + 1];
    float4 acc = ((const float4*)(lin + (long long)v * 128))[lane];
    float dv2 = dv * dv;
    acc.x *= dv2; acc.y *= dv2; acc.z *= dv2; acc.w *= dv2;

    for (int jb = beg; jb < end; jb += 32) {
        int j = jb + lane;
        int idx = (j < end) ? csr_src[j] : 0;
        float dn = (j < end) ? dinv[idx] * dv : 0.f;  // premultiplied norm
        int m = end - jb;
        if (m > 32) m = 32;
        int k = 0;
        for (; k + 8 <= m; k += 8) {
            int s0 = __shfl(idx, k + 0, 32); float n0 = __shfl(dn, k + 0, 32);
            int s1 = __shfl(idx, k + 1, 32); float n1 = __shfl(dn, k + 1, 32);
            int s2 = __shfl(idx, k + 2, 32); float n2 = __shfl(dn, k + 2, 32);
            int s3 = __shfl(idx, k + 3, 32); float n3 = __shfl(dn, k + 3, 32);
            int s4 = __shfl(idx, k + 4, 32); float n4 = __shfl(dn, k + 4, 32);
            int s5 = __shfl(idx, k + 5, 32); float n5 = __shfl(dn, k + 5, 32);
            int s6 = __shfl(idx, k + 6, 32); float n6 = __shfl(dn, k + 6, 32);
            int s7 = __shfl(idx, k + 7, 32); float n7 = __shfl(dn, k + 7, 32);
            float4 v0 = ((const float4*)(lin + (long long)s0 * 128))[lane];
            float4 v1 = ((const float4*)(lin + (long long)s1 * 128))[lane];
            float4 v2 = ((const float4*)(lin + (long long)s2 * 128))[lane];
            float4 v3 = ((const float4*)(lin + (long long)s3 * 128))[lane];
            float4 v4 = ((const float4*)(lin + (long long)s4 * 128))[lane];
            float4 v5 = ((const float4*)(lin + (long long)s5 * 128))[lane];
            float4 v6 = ((const float4*)(lin + (long long)s6 * 128))[lane];
            float4 v7 = ((const float4*)(lin + (long long)s7 * 128))[lane];
            acc.x += v0.x * n0 + v1.x * n1 + v2.x * n2 + v3.x * n3
                   + v4.x * n4 + v5.x * n5 + v6.x * n6 + v7.x * n7;
            acc.y += v0.y * n0 + v1.y * n1 + v2.y * n2 + v3.y * n3
                   + v4.y * n4 + v5.y * n5 + v6.y * n6 + v7.y * n7;
            acc.z += v0.z * n0 + v1.z * n1 + v2.z * n2 + v3.z * n3
                   + v4.z * n4 + v5.z * n5 + v6.z * n6 + v7.z * n7;
            acc.w += v0.w * n0 + v1.w * n1 + v2.w * n2 + v3.w * n3
                   + v4.w * n4 + v5.w * n5 + v6.w * n6 + v7.w * n7;
        }
        for (; k + 4 <= m; k += 4) {
            int s0 = __shfl(idx, k + 0, 32); float n0 = __shfl(dn, k + 0, 32);
            int s1 = __shfl(idx, k + 1, 32); float n1 = __shfl(dn, k + 1, 32);
            int s2 = __shfl(idx, k + 2, 32); float n2 = __shfl(dn, k + 2, 32);
            int s3 = __shfl(idx, k + 3, 32); float n3 = __shfl(dn, k + 3, 32);
            float4 v0 = ((const float4*)(lin + (long long)s0 * 128))[lane];
            float4 v1 = ((const float4*)(lin + (long long)s1 * 128))[lane];
            float4 v2 = ((const float4*)(lin + (long long)s2 * 128))[lane];
            float4 v3 = ((const float4*)(lin + (long long)s3 * 128))[lane];
            acc.x += v0.x * n0 + v1.x * n1 + v2.x * n2 + v3.x * n3;
            acc.y += v0.y * n0 + v1.y * n1 + v2.y * n2 + v3.y * n3;
            acc.z += v0.z * n0 + v1.z * n1 + v2.z * n2 + v3.z * n3;
            acc.w += v0.w * n0 + v1.w * n1 + v2.w * n2 + v3.w * n3;
        }
        for (; k < m; ++k) {
            int s0 = __shfl(idx, k, 32);
            float n0 = __shfl(dn, k, 32);
            float4 v0 = ((const float4*)(lin + (long long)s0 * 128))[lane];
            acc.x += v0.x * n0;
            acc.y += v0.y * n0;
            acc.z += v0.z * n0;
            acc.w += v0.w * n0;
        }
    }
    float4 bb = ((const float4*)b)[lane];
    acc.x += bb.x; acc.y += bb.y; acc.z += bb.z; acc.w += bb.w;
    ((float4*)(h + (long long)v * 128))[lane] = acc;
}

// Per-column sum / sumsq of h (streaming, block-reduced, 256-deep atomic chains).
__global__ __launch_bounds__(256) void bnstats_kernel(const float* __restrict__ h,
                                                      float* __restrict__ colsum,
                                                      float* __restrict__ colsumsq, int n) {
    __shared__ float4 ssum[256];
    __shared__ float4 ssq[256];
    int t = threadIdx.x;
    int lane = t & 31;
    int rg = t >> 5;
    float4 ls = make_float4(0.f, 0.f, 0.f, 0.f);
    float4 lq = make_float4(0.f, 0.f, 0.f, 0.f);
    for (int r = blockIdx.x * 8 + rg; r < n; r += gridDim.x * 8) {
        float4 hv = ((const float4*)(h + (long long)r * 128))[lane];
        ls.x += hv.x; ls.y += hv.y; ls.z += hv.z; ls.w += hv.w;
        lq.x += hv.x * hv.x; lq.y += hv.y * hv.y;
        lq.z += hv.z * hv.z; lq.w += hv.w * hv.w;
    }
    ssum[t] = ls;
    ssq[t] = lq;
    __syncthreads();
    if (t < 32) {
        float4 a = ssum[t];
        float4 q = ssq[t];
        for (int g2 = 1; g2 < 8; ++g2) {
            float4 a2 = ssum[g2 * 32 + t];
            float4 q2 = ssq[g2 * 32 + t];
            a.x += a2.x; a.y += a2.y; a.z += a2.z; a.w += a2.w;
            q.x += q2.x; q.y += q2.y; q.z += q2.z; q.w += q2.w;
        }
        atomicAdd(&colsum[t * 4 + 0], a.x);
        atomicAdd(&colsum[t * 4 + 1], a.y);
        atomicAdd(&colsum[t * 4 + 2], a.z);
        atomicAdd(&colsum[t * 4 + 3], a.w);
        atomicAdd(&colsumsq[t * 4 + 0], q.x);
        atomicAdd(&colsumsq[t * 4 + 1], q.y);
        atomicAdd(&colsumsq[t * 4 + 2], q.z);
        atomicAdd(&colsumsq[t * 4 + 3], q.w);
    }
}

// out = relu((h-mean)*rsqrt(var+eps)*gamma + beta) + x    (float4 over columns)
__global__ __launch_bounds__(256) void out_kernel(const float* __restrict__ h,
                                                  const float* __restrict__ x,
                                                  const float* __restrict__ colsum,
                                                  const float* __restrict__ colsumsq,
                                                  const float* __restrict__ gamma,
                                                  const float* __restrict__ beta,
                                                  float* __restrict__ out, int n) {
    long long total4 = (long long)n * 32;
    long long i = (long long)blockIdx.x * 256 + threadIdx.x;
    long long stride = (long long)gridDim.x * 256;
    float inv_n = 1.0f / (float)n;
    for (; i < total4; i += stride) {
        int c4 = (int)(i & 31);
        float4 cs = ((const float4*)colsum)[c4];
        float4 cq = ((const float4*)colsumsq)[c4];
        float4 g = ((const float4*)gamma)[c4];
        float4 bt = ((const float4*)beta)[c4];
        float4 hv = ((const float4*)h)[i];
        float4 xv = ((const float4*)x)[i];
        float m0 = cs.x * inv_n, m1 = cs.y * inv_n, m2 = cs.z * inv_n, m3 = cs.w * inv_n;
        float r0 = rsqrtf(cq.x * inv_n - m0 * m0 + BN_EPS);
        float r1 = rsqrtf(cq.y * inv_n - m1 * m1 + BN_EPS);
        float r2 = rsqrtf(cq.z * inv_n - m2 * m2 + BN_EPS);
        float r3 = rsqrtf(cq.w * inv_n - m3 * m3 + BN_EPS);
        float4 o;
        o.x = fmaxf((hv.x - m0) * r0 * g.x + bt.x, 0.f) + xv.x;
        o.y = fmaxf((hv.y - m1) * r1 * g.y + bt.y, 0.f) + xv.y;
        o.z = fmaxf((hv.z - m2) * r2 * g.z + bt.z, 0.f) + xv.z;
        o.w = fmaxf((hv.w - m3) * r3 * g.w + bt.w, 0.f) + xv.w;
        ((float4*)out)[i] = o;
    }
}

extern "C" void kernel_launch(void* const* d_in, const int* in_sizes, int n_in,
                              void* d_out, int out_size, void* d_ws, size_t ws_size,
                              hipStream_t stream) {
    const float* x     = (const float*)d_in[0];
    const void*  eidx  = d_in[1];
    const float* W     = (const float*)d_in[2];
    const float* b     = (const float*)d_in[3];
    const float* gamma = (const float*)d_in[4];
    const float* beta  = (const float*)d_in[5];
    float* out = (float*)d_out;

    int n = in_sizes[0] / 128;
    int E = in_sizes[1] / 2;

    float* ws = (float*)d_ws;
    long long nd = (long long)n * 128;
    float* lin       = ws;
    float* h         = ws + nd;
    int*   deg_i     = (int*)(ws + 2 * nd);
    float* colsum    = (float*)(deg_i + n);
    float* colsumsq  = colsum + 128;
    int*   row_start = (int*)(colsumsq + 128);
    int*   cursor    = row_start + (n + 1);
    int*   csr_src   = cursor + n;
    float* dinv      = (float*)(csr_src + E);
    int*   flag      = (int*)(dinv + n);
    int*   bsum      = flag + 1;

    detect_i64_kernel<<<1, 64, 0, stream>>>((const unsigned*)eidx, flag);

    // zero deg_i + colsum + colsumsq (contiguous)
    zero_kernel<<<512, 256, 0, stream>>>(deg_i, n + 256);

    deg_kernel<<<(E + 255) / 256, 256, 0, stream>>>(eidx, flag, deg_i, E);

    int nb = (n + 1023) / 1024;
    scan1_kernel<<<nb, 256, 0, stream>>>(deg_i, bsum, n);
    scan2_kernel<<<1, 1024, 0, stream>>>(bsum, nb, row_start, n, E);
    scan3_kernel<<<nb, 256, 0, stream>>>(deg_i, bsum, row_start, cursor, dinv, n);

    fill_kernel<<<(E + 255) / 256, 256, 0, stream>>>(eidx, flag, cursor, csr_src, E);

    gemm_kernel<<<512, 256, 0, stream>>>(x, W, lin, n);

    gather_kernel<<<(n + 7) / 8, 256, 0, stream>>>(row_start, csr_src, lin, dinv, b, h, n);

    bnstats_kernel<<<256, 256, 0, stream>>>(h, colsum, colsumsq, n);

    out_kernel<<<2048, 256, 0, stream>>>(h, x, colsum, colsumsq, gamma, beta, out, n);
}

// Round 8
// 212.003 us; speedup vs baseline: 2.4265x; 1.2962x over previous
//
#include <hip/hip_runtime.h>
#include <hip/hip_fp16.h>

#define BN_EPS 1e-5f
#define CAP 64          // bucket capacity per node (deg ~ Poisson(12); P(>64) ~ 1e-30)
#define OVF_CAP 65536   // overflow edge list capacity
#define NREP 64         // replicated BN-stat accumulators

// ---------------------------------------------------------------------------
// ws layout (4-byte units):
//   lin_h   [n*64]   (half[n*128], x@W in fp16)
//   h       [n*128]  float (pre-BN activations)
//   cnt     [n]      int   (degree counters; zeroed)
//   cps     [NREP*128] float (replicated col sums; zeroed)
//   cpq     [NREP*128] float (replicated col sumsq; zeroed)
//   ovf_cnt [1]      int   (zeroed)
//   flag    [1]      int   (1 if edge_index is int64)
//   ovf_list[2*OVF_CAP] int
//   bucket  [n*CAP]  int
//   scale   [128], shift [128] float
// ---------------------------------------------------------------------------

// zero cnt+cps+cpq+ovf_cnt; block 0 detects int32-vs-int64 edge dtype.
__global__ __launch_bounds__(256) void prep_kernel(const unsigned* __restrict__ e32,
                                                   int* __restrict__ zbase, int zcount,
                                                   int* __restrict__ flag) {
    int i = blockIdx.x * 256 + threadIdx.x;
    for (; i < zcount; i += gridDim.x * 256) zbase[i] = 0;
    if (blockIdx.x == 0 && threadIdx.x < 64) {
        // int64 indices < 2^31: every odd 32-bit word is 0.
        unsigned v = e32[2 * threadIdx.x + 1];
        unsigned long long b = __ballot(v == 0u);
        if (threadIdx.x == 0) *flag = (b == ~0ULL) ? 1 : 0;
    }
}

// count degree + place src into dst's bucket row in one atomic.
__global__ __launch_bounds__(256) void fill_kernel(const void* __restrict__ eidx,
                                                   const int* __restrict__ flag,
                                                   int* __restrict__ cnt,
                                                   int* __restrict__ bucket,
                                                   int* __restrict__ ovf_cnt,
                                                   int* __restrict__ ovf_list, int E) {
    int base = (blockIdx.x * 256 + threadIdx.x) * 4;
    bool f = (*flag != 0);
#pragma unroll
    for (int u = 0; u < 4; ++u) {
        int e = base + u;
        if (e >= E) break;
        int src, dst;
        if (f) {
            const long long* p = (const long long*)eidx;
            src = (int)p[e];
            dst = (int)p[(long long)E + e];
        } else {
            const int* p = (const int*)eidx;
            src = p[e];
            dst = p[E + e];
        }
        int pos = atomicAdd(&cnt[dst], 1);
        if (pos < CAP) {
            bucket[(long long)dst * CAP + pos] = src;
        } else {
            int o = atomicAdd(ovf_cnt, 1);
            if (o < OVF_CAP) { ovf_list[2 * o] = dst; ovf_list[2 * o + 1] = src; }
        }
    }
}

// lin_h = fp16(x @ W). W (64KB) + 32-row x tile (16KB) in LDS.
// Thread (c4 = t&31, rg = t>>5): 4 rows x 4 cols.
__global__ __launch_bounds__(256, 2) void gemm_kernel(const float* __restrict__ x,
                                                      const float* __restrict__ W,
                                                      __half* __restrict__ lin_h, int n) {
    __shared__ float Ws[128 * 128];
    __shared__ float xs[32 * 128];
    int t = threadIdx.x;
    for (int i = t; i < 4096; i += 256) ((float4*)Ws)[i] = ((const float4*)W)[i];

    int c4 = t & 31;
    int rg = t >> 5;
    int nchunk = (n + 31) >> 5;

    for (int ch = blockIdx.x; ch < nchunk; ch += gridDim.x) {
        int r0 = ch << 5;
        __syncthreads();  // also covers Ws staging on first iteration
        for (int i = t; i < 1024; i += 256) {
            int r = r0 + (i >> 5);
            ((float4*)xs)[i] = (r < n) ? ((const float4*)x)[(long long)r * 32 + (i & 31)]
                                       : make_float4(0.f, 0.f, 0.f, 0.f);
        }
        __syncthreads();

        const float4* xr0 = (const float4*)(xs + (rg * 4 + 0) * 128);
        const float4* xr1 = (const float4*)(xs + (rg * 4 + 1) * 128);
        const float4* xr2 = (const float4*)(xs + (rg * 4 + 2) * 128);
        const float4* xr3 = (const float4*)(xs + (rg * 4 + 3) * 128);
        float4 a0 = make_float4(0.f, 0.f, 0.f, 0.f);
        float4 a1 = a0, a2 = a0, a3 = a0;

        for (int k4 = 0; k4 < 32; ++k4) {
            float4 xv0 = xr0[k4];
            float4 xv1 = xr1[k4];
            float4 xv2 = xr2[k4];
            float4 xv3 = xr3[k4];
            int kb = k4 * 4;
            float4 w0 = ((const float4*)(Ws + (kb + 0) * 128))[c4];
            float4 w1 = ((const float4*)(Ws + (kb + 1) * 128))[c4];
            float4 w2 = ((const float4*)(Ws + (kb + 2) * 128))[c4];
            float4 w3 = ((const float4*)(Ws + (kb + 3) * 128))[c4];
#define ACC(A, XV)                                                          \
            A.x += XV.x * w0.x + XV.y * w1.x + XV.z * w2.x + XV.w * w3.x;   \
            A.y += XV.x * w0.y + XV.y * w1.y + XV.z * w2.y + XV.w * w3.y;   \
            A.z += XV.x * w0.z + XV.y * w1.z + XV.z * w2.z + XV.w * w3.z;   \
            A.w += XV.x * w0.w + XV.y * w1.w + XV.z * w2.w + XV.w * w3.w
            ACC(a0, xv0);
            ACC(a1, xv1);
            ACC(a2, xv2);
            ACC(a3, xv3);
#undef ACC
        }
        int r = r0 + rg * 4;
#define STORE_ROW(RI, A)                                                     \
        if (r + RI < n) {                                                    \
            union { __half2 h2[2]; uint2 u; } cv;                            \
            cv.h2[0] = __floats2half2_rn(A.x, A.y);                          \
            cv.h2[1] = __floats2half2_rn(A.z, A.w);                          \
            ((uint2*)(lin_h + (long long)(r + RI) * 128))[c4] = cv.u;        \
        }
        STORE_ROW(0, a0);
        STORE_ROW(1, a1);
        STORE_ROW(2, a2);
        STORE_ROW(3, a3);
#undef STORE_ROW
    }
}

__device__ __forceinline__ float4 load_row_f16(const __half* __restrict__ lin_h,
                                               long long row, int lane) {
    uint2 raw = ((const uint2*)(lin_h + row * 128))[lane];
    float2 f0 = __half22float2(*(__half2*)&raw.x);
    float2 f1 = __half22float2(*(__half2*)&raw.y);
    return make_float4(f0.x, f0.y, f1.x, f1.y);
}

// One 32-lane group per node; dinv computed on the fly from cnt.
// h[v] = sum_{s in bucket(v)} lin[s]*dinv[s]*dinv[v] + lin[v]*dinv[v]^2 + b
// BN col-stats accumulated into NREP replicated slots (no serial tail).
__global__ __launch_bounds__(256) void gather_kernel(const int* __restrict__ cnt,
                                                     const int* __restrict__ bucket,
                                                     const __half* __restrict__ lin_h,
                                                     const float* __restrict__ b,
                                                     float* __restrict__ h,
                                                     float* __restrict__ cps,
                                                     float* __restrict__ cpq, int n) {
    __shared__ float4 ssum[256];
    __shared__ float4 ssq[256];
    int t = threadIdx.x;
    int lane = t & 31;
    int grp = t >> 5;  // 8 groups of 32
    int v = blockIdx.x * 8 + grp;
    float4 lsum = make_float4(0.f, 0.f, 0.f, 0.f);
    float4 lsq = make_float4(0.f, 0.f, 0.f, 0.f);

    if (v < n) {
        int deg = cnt[v];
        float dv = rsqrtf((float)deg + 1.0f);  // +1 self-loop
        int m_all = deg < CAP ? deg : CAP;
        float4 acc = load_row_f16(lin_h, v, lane);
        float dv2 = dv * dv;
        acc.x *= dv2; acc.y *= dv2; acc.z *= dv2; acc.w *= dv2;
        const int* brow = bucket + (long long)v * CAP;

        for (int jb = 0; jb < m_all; jb += 32) {
            int j = jb + lane;
            int idx = (j < m_all) ? brow[j] : 0;
            float dn = (j < m_all) ? rsqrtf((float)cnt[idx] + 1.0f) * dv : 0.f;
            int m = m_all - jb;
            if (m > 32) m = 32;
            int k = 0;
            for (; k + 8 <= m; k += 8) {
                int s0 = __shfl(idx, k + 0, 32); float n0 = __shfl(dn, k + 0, 32);
                int s1 = __shfl(idx, k + 1, 32); float n1 = __shfl(dn, k + 1, 32);
                int s2 = __shfl(idx, k + 2, 32); float n2 = __shfl(dn, k + 2, 32);
                int s3 = __shfl(idx, k + 3, 32); float n3 = __shfl(dn, k + 3, 32);
                int s4 = __shfl(idx, k + 4, 32); float n4 = __shfl(dn, k + 4, 32);
                int s5 = __shfl(idx, k + 5, 32); float n5 = __shfl(dn, k + 5, 32);
                int s6 = __shfl(idx, k + 6, 32); float n6 = __shfl(dn, k + 6, 32);
                int s7 = __shfl(idx, k + 7, 32); float n7 = __shfl(dn, k + 7, 32);
                float4 v0 = load_row_f16(lin_h, s0, lane);
                float4 v1 = load_row_f16(lin_h, s1, lane);
                float4 v2 = load_row_f16(lin_h, s2, lane);
                float4 v3 = load_row_f16(lin_h, s3, lane);
                float4 v4 = load_row_f16(lin_h, s4, lane);
                float4 v5 = load_row_f16(lin_h, s5, lane);
                float4 v6 = load_row_f16(lin_h, s6, lane);
                float4 v7 = load_row_f16(lin_h, s7, lane);
                acc.x += v0.x * n0 + v1.x * n1 + v2.x * n2 + v3.x * n3
                       + v4.x * n4 + v5.x * n5 + v6.x * n6 + v7.x * n7;
                acc.y += v0.y * n0 + v1.y * n1 + v2.y * n2 + v3.y * n3
                       + v4.y * n4 + v5.y * n5 + v6.y * n6 + v7.y * n7;
                acc.z += v0.z * n0 + v1.z * n1 + v2.z * n2 + v3.z * n3
                       + v4.z * n4 + v5.z * n5 + v6.z * n6 + v7.z * n7;
                acc.w += v0.w * n0 + v1.w * n1 + v2.w * n2 + v3.w * n3
                       + v4.w * n4 + v5.w * n5 + v6.w * n6 + v7.w * n7;
            }
            for (; k + 4 <= m; k += 4) {
                int s0 = __shfl(idx, k + 0, 32); float n0 = __shfl(dn, k + 0, 32);
                int s1 = __shfl(idx, k + 1, 32); float n1 = __shfl(dn, k + 1, 32);
                int s2 = __shfl(idx, k + 2, 32); float n2 = __shfl(dn, k + 2, 32);
                int s3 = __shfl(idx, k + 3, 32); float n3 = __shfl(dn, k + 3, 32);
                float4 v0 = load_row_f16(lin_h, s0, lane);
                float4 v1 = load_row_f16(lin_h, s1, lane);
                float4 v2 = load_row_f16(lin_h, s2, lane);
                float4 v3 = load_row_f16(lin_h, s3, lane);
                acc.x += v0.x * n0 + v1.x * n1 + v2.x * n2 + v3.x * n3;
                acc.y += v0.y * n0 + v1.y * n1 + v2.y * n2 + v3.y * n3;
                acc.z += v0.z * n0 + v1.z * n1 + v2.z * n2 + v3.z * n3;
                acc.w += v0.w * n0 + v1.w * n1 + v2.w * n2 + v3.w * n3;
            }
            for (; k < m; ++k) {
                int s0 = __shfl(idx, k, 32);
                float n0 = __shfl(dn, k, 32);
                float4 v0 = load_row_f16(lin_h, s0, lane);
                acc.x += v0.x * n0;
                acc.y += v0.y * n0;
                acc.z += v0.z * n0;
                acc.w += v0.w * n0;
            }
        }
        float4 bb = ((const float4*)b)[lane];
        acc.x += bb.x; acc.y += bb.y; acc.z += bb.z; acc.w += bb.w;
        ((float4*)(h + (long long)v * 128))[lane] = acc;
        lsum = acc;
        lsq = make_float4(acc.x * acc.x, acc.y * acc.y, acc.z * acc.z, acc.w * acc.w);
    }

    ssum[t] = lsum;
    ssq[t] = lsq;
    __syncthreads();
    if (t < 32) {
        float4 a = ssum[t];
        float4 q = ssq[t];
        for (int g2 = 1; g2 < 8; ++g2) {
            float4 a2 = ssum[g2 * 32 + t];
            float4 q2 = ssq[g2 * 32 + t];
            a.x += a2.x; a.y += a2.y; a.z += a2.z; a.w += a2.w;
            q.x += q2.x; q.y += q2.y; q.z += q2.z; q.w += q2.w;
        }
        int rep = (blockIdx.x & (NREP - 1)) * 128;
        atomicAdd(&cps[rep + t * 4 + 0], a.x);
        atomicAdd(&cps[rep + t * 4 + 1], a.y);
        atomicAdd(&cps[rep + t * 4 + 2], a.z);
        atomicAdd(&cps[rep + t * 4 + 3], a.w);
        atomicAdd(&cpq[rep + t * 4 + 0], q.x);
        atomicAdd(&cpq[rep + t * 4 + 1], q.y);
        atomicAdd(&cpq[rep + t * 4 + 2], q.z);
        atomicAdd(&cpq[rep + t * 4 + 3], q.w);
    }
}

// Adds overflow-edge contributions into h (loops zero times in practice).
__global__ __launch_bounds__(256) void fixup_kernel(const int* __restrict__ ovf_cnt,
                                                    const int* __restrict__ ovf_list,
                                                    const int* __restrict__ cnt,
                                                    const __half* __restrict__ lin_h,
                                                    float* __restrict__ h) {
    int nov = *ovf_cnt;
    if (nov > OVF_CAP) nov = OVF_CAP;
    int t = threadIdx.x;
    int lane = t & 31;
    int grp = t >> 5;
    for (int i = grp; i < nov; i += 8) {
        int dst = ovf_list[2 * i];
        int src = ovf_list[2 * i + 1];
        float norm = rsqrtf((float)cnt[src] + 1.0f) * rsqrtf((float)cnt[dst] + 1.0f);
        float4 v0 = load_row_f16(lin_h, src, lane);
        float* hp = h + (long long)dst * 128 + lane * 4;
        atomicAdd(hp + 0, v0.x * norm);
        atomicAdd(hp + 1, v0.y * norm);
        atomicAdd(hp + 2, v0.z * norm);
        atomicAdd(hp + 3, v0.w * norm);
    }
}

// Fast path: reduce NREP replicated stats -> scale/shift.
// Slow path (overflow occurred): re-stream h for exact stats.
__global__ __launch_bounds__(256) void reduce_kernel(const int* __restrict__ ovf_cnt,
                                                     const float* __restrict__ cps,
                                                     const float* __restrict__ cpq,
                                                     const float* __restrict__ h,
                                                     const float* __restrict__ gamma,
                                                     const float* __restrict__ beta,
                                                     float* __restrict__ scale,
                                                     float* __restrict__ shift, int n) {
    __shared__ float s0[256];
    __shared__ float s1[256];
    int t = threadIdx.x;
    int col = t & 127;
    int hf = t >> 7;
    float s = 0.f, q = 0.f;
    if (*ovf_cnt == 0) {
        for (int r = hf * (NREP / 2); r < (hf + 1) * (NREP / 2); ++r) {
            s += cps[r * 128 + col];
            q += cpq[r * 128 + col];
        }
    } else {
        for (long long r = hf; r < n; r += 2) {
            float hv = h[r * 128 + col];
            s += hv;
            q += hv * hv;
        }
    }
    s0[t] = s;
    s1[t] = q;
    __syncthreads();
    if (t < 128) {
        float su = s0[t] + s0[t + 128];
        float qu = s1[t] + s1[t + 128];
        float m = su / (float)n;
        float var = qu / (float)n - m * m;
        float sc = gamma[t] * rsqrtf(var + BN_EPS);
        scale[t] = sc;
        shift[t] = beta[t] - m * sc;
    }
}

// out = relu(h*scale + shift) + x
__global__ __launch_bounds__(256) void out_kernel(const float* __restrict__ h,
                                                  const float* __restrict__ x,
                                                  const float* __restrict__ scale,
                                                  const float* __restrict__ shift,
                                                  float* __restrict__ out, int n) {
    long long total4 = (long long)n * 32;
    long long i = (long long)blockIdx.x * 256 + threadIdx.x;
    long long stride = (long long)gridDim.x * 256;
    for (; i < total4; i += stride) {
        int c4 = (int)(i & 31);
        float4 sc = ((const float4*)scale)[c4];
        float4 sh = ((const float4*)shift)[c4];
        float4 hv = ((const float4*)h)[i];
        float4 xv = ((const float4*)x)[i];
        float4 o;
        o.x = fmaxf(hv.x * sc.x + sh.x, 0.f) + xv.x;
        o.y = fmaxf(hv.y * sc.y + sh.y, 0.f) + xv.y;
        o.z = fmaxf(hv.z * sc.z + sh.z, 0.f) + xv.z;
        o.w = fmaxf(hv.w * sc.w + sh.w, 0.f) + xv.w;
        ((float4*)out)[i] = o;
    }
}

extern "C" void kernel_launch(void* const* d_in, const int* in_sizes, int n_in,
                              void* d_out, int out_size, void* d_ws, size_t ws_size,
                              hipStream_t stream) {
    const float* x     = (const float*)d_in[0];
    const void*  eidx  = d_in[1];
    const float* W     = (const float*)d_in[2];
    const float* b     = (const float*)d_in[3];
    const float* gamma = (const float*)d_in[4];
    const float* beta  = (const float*)d_in[5];
    float* out = (float*)d_out;

    int n = in_sizes[0] / 128;
    int E = in_sizes[1] / 2;

    float* ws = (float*)d_ws;
    long long nd = (long long)n * 128;
    __half* lin_h   = (__half*)ws;                    // n*64 floats worth
    float* h        = ws + (long long)n * 64;
    int*   cnt      = (int*)(h + nd);
    float* cps      = (float*)(cnt + n);
    float* cpq      = cps + NREP * 128;
    int*   ovf_cnt  = (int*)(cpq + NREP * 128);
    int*   flag     = ovf_cnt + 1;
    int*   ovf_list = flag + 1;
    int*   bucket   = ovf_list + 2 * OVF_CAP;
    float* scale    = (float*)(bucket + (long long)n * CAP);
    float* shift    = scale + 128;

    // zero range: cnt + cps + cpq + ovf_cnt (contiguous)
    int zcount = n + 2 * NREP * 128 + 1;
    prep_kernel<<<64, 256, 0, stream>>>((const unsigned*)eidx, cnt, zcount, flag);

    fill_kernel<<<(E + 1023) / 1024, 256, 0, stream>>>(eidx, flag, cnt, bucket,
                                                       ovf_cnt, ovf_list, E);

    gemm_kernel<<<512, 256, 0, stream>>>(x, W, lin_h, n);

    gather_kernel<<<(n + 7) / 8, 256, 0, stream>>>(cnt, bucket, lin_h, b, h,
                                                   cps, cpq, n);

    fixup_kernel<<<1, 256, 0, stream>>>(ovf_cnt, ovf_list, cnt, lin_h, h);

    reduce_kernel<<<1, 256, 0, stream>>>(ovf_cnt, cps, cpq, h, gamma, beta,
                                         scale, shift, n);

    out_kernel<<<2048, 256, 0, stream>>>(h, x, scale, shift, out, n);
}

// Round 9
// 205.121 us; speedup vs baseline: 2.5079x; 1.0336x over previous
//
#include <hip/hip_runtime.h>
#include <hip/hip_fp16.h>

#define BN_EPS 1e-5f
#define CAP 64          // bucket capacity per node (deg ~ Poisson(12); P(>64) ~ 1e-30)
#define OVF_CAP 65536   // overflow edge list capacity
#define NREP 64         // replicated BN-stat accumulators

// ---------------------------------------------------------------------------
// ws layout (4-byte units):
//   lin_h   [n*64]   (half[n*128], x@W in fp16)
//   h       [n*128]  float (pre-BN activations)
//   cnt     [n]      int   (degree counters; zeroed)
//   cps     [NREP*128] float (replicated col sums; zeroed)
//   cpq     [NREP*128] float (replicated col sumsq; zeroed)
//   ovf_cnt [1]      int   (zeroed)
//   flag    [1]      int   (1 if edge_index is int64)
//   ovf_list[2*OVF_CAP] int
//   bucket  [n*CAP]  int
//   scale   [128], shift [128] float
// ---------------------------------------------------------------------------

// zero cnt+cps+cpq+ovf_cnt; block 0 detects int32-vs-int64 edge dtype.
__global__ __launch_bounds__(256) void prep_kernel(const unsigned* __restrict__ e32,
                                                   int* __restrict__ zbase, int zcount,
                                                   int* __restrict__ flag) {
    int i = blockIdx.x * 256 + threadIdx.x;
    for (; i < zcount; i += gridDim.x * 256) zbase[i] = 0;
    if (blockIdx.x == 0 && threadIdx.x < 64) {
        // int64 indices < 2^31: every odd 32-bit word is 0.
        unsigned v = e32[2 * threadIdx.x + 1];
        unsigned long long b = __ballot(v == 0u);
        if (threadIdx.x == 0) *flag = (b == ~0ULL) ? 1 : 0;
    }
}

// count degree + place src into dst's bucket row in one atomic. 1 edge/thread.
__global__ __launch_bounds__(256) void fill_kernel(const void* __restrict__ eidx,
                                                   const int* __restrict__ flag,
                                                   int* __restrict__ cnt,
                                                   int* __restrict__ bucket,
                                                   int* __restrict__ ovf_cnt,
                                                   int* __restrict__ ovf_list, int E) {
    int e = blockIdx.x * 256 + threadIdx.x;
    if (e >= E) return;
    int src, dst;
    if (*flag) {
        const long long* p = (const long long*)eidx;
        src = (int)p[e];
        dst = (int)p[(long long)E + e];
    } else {
        const int* p = (const int*)eidx;
        src = p[e];
        dst = p[E + e];
    }
    int pos = atomicAdd(&cnt[dst], 1);
    if (pos < CAP) {
        bucket[(long long)dst * CAP + pos] = src;
    } else {
        int o = atomicAdd(ovf_cnt, 1);
        if (o < OVF_CAP) { ovf_list[2 * o] = dst; ovf_list[2 * o + 1] = src; }
    }
}

__device__ __forceinline__ float4 lds_w4(const __half* __restrict__ Ws, int row, int c4) {
    union { uint2 u; __half2 h2[2]; } cv;
    cv.u = ((const uint2*)(Ws + row * 128))[c4];
    float2 f0 = __half22float2(cv.h2[0]);
    float2 f1 = __half22float2(cv.h2[1]);
    return make_float4(f0.x, f0.y, f1.x, f1.y);
}

// lin_h = fp16(x @ W). W staged as fp16 in LDS (32KB) + 32-row fp32 x tile (16KB)
// = 48KB -> 3 blocks/CU. Thread (c4 = t&31, rg = t>>5): 4 rows x 4 cols.
__global__ __launch_bounds__(256, 3) void gemm_kernel(const float* __restrict__ x,
                                                      const float* __restrict__ W,
                                                      __half* __restrict__ lin_h, int n) {
    __shared__ __half Ws[128 * 128];  // 32 KB
    __shared__ float xs[32 * 128];    // 16 KB
    int t = threadIdx.x;
    for (int i = t; i < 4096; i += 256) {
        float4 w = ((const float4*)W)[i];
        union { __half2 h2[2]; uint2 u; } cv;
        cv.h2[0] = __floats2half2_rn(w.x, w.y);
        cv.h2[1] = __floats2half2_rn(w.z, w.w);
        ((uint2*)Ws)[i] = cv.u;
    }

    int c4 = t & 31;
    int rg = t >> 5;
    int nchunk = (n + 31) >> 5;

    for (int ch = blockIdx.x; ch < nchunk; ch += gridDim.x) {
        int r0 = ch << 5;
        __syncthreads();  // also covers Ws staging on first iteration
        for (int i = t; i < 1024; i += 256) {
            int r = r0 + (i >> 5);
            ((float4*)xs)[i] = (r < n) ? ((const float4*)x)[(long long)r * 32 + (i & 31)]
                                       : make_float4(0.f, 0.f, 0.f, 0.f);
        }
        __syncthreads();

        const float4* xr0 = (const float4*)(xs + (rg * 4 + 0) * 128);
        const float4* xr1 = (const float4*)(xs + (rg * 4 + 1) * 128);
        const float4* xr2 = (const float4*)(xs + (rg * 4 + 2) * 128);
        const float4* xr3 = (const float4*)(xs + (rg * 4 + 3) * 128);
        float4 a0 = make_float4(0.f, 0.f, 0.f, 0.f);
        float4 a1 = a0, a2 = a0, a3 = a0;

        for (int k4 = 0; k4 < 32; ++k4) {
            float4 xv0 = xr0[k4];
            float4 xv1 = xr1[k4];
            float4 xv2 = xr2[k4];
            float4 xv3 = xr3[k4];
            int kb = k4 * 4;
            float4 w0 = lds_w4(Ws, kb + 0, c4);
            float4 w1 = lds_w4(Ws, kb + 1, c4);
            float4 w2 = lds_w4(Ws, kb + 2, c4);
            float4 w3 = lds_w4(Ws, kb + 3, c4);
#define ACC(A, XV)                                                          \
            A.x += XV.x * w0.x + XV.y * w1.x + XV.z * w2.x + XV.w * w3.x;   \
            A.y += XV.x * w0.y + XV.y * w1.y + XV.z * w2.y + XV.w * w3.y;   \
            A.z += XV.x * w0.z + XV.y * w1.z + XV.z * w2.z + XV.w * w3.z;   \
            A.w += XV.x * w0.w + XV.y * w1.w + XV.z * w2.w + XV.w * w3.w
            ACC(a0, xv0);
            ACC(a1, xv1);
            ACC(a2, xv2);
            ACC(a3, xv3);
#undef ACC
        }
        int r = r0 + rg * 4;
#define STORE_ROW(RI, A)                                                     \
        if (r + RI < n) {                                                    \
            union { __half2 h2[2]; uint2 u; } cv;                            \
            cv.h2[0] = __floats2half2_rn(A.x, A.y);                          \
            cv.h2[1] = __floats2half2_rn(A.z, A.w);                          \
            ((uint2*)(lin_h + (long long)(r + RI) * 128))[c4] = cv.u;        \
        }
        STORE_ROW(0, a0);
        STORE_ROW(1, a1);
        STORE_ROW(2, a2);
        STORE_ROW(3, a3);
#undef STORE_ROW
    }
}

__device__ __forceinline__ float4 load_row_f16(const __half* __restrict__ lin_h,
                                               long long row, int lane) {
    uint2 raw = ((const uint2*)(lin_h + row * 128))[lane];
    float2 f0 = __half22float2(*(__half2*)&raw.x);
    float2 f1 = __half22float2(*(__half2*)&raw.y);
    return make_float4(f0.x, f0.y, f1.x, f1.y);
}

// One 32-lane group per node; dinv computed on the fly from cnt.
// h[v] = sum_{s in bucket(v)} lin[s]*dinv[s]*dinv[v] + lin[v]*dinv[v]^2 + b
// BN col-stats accumulated into NREP replicated slots (no serial tail).
__global__ __launch_bounds__(256) void gather_kernel(const int* __restrict__ cnt,
                                                     const int* __restrict__ bucket,
                                                     const __half* __restrict__ lin_h,
                                                     const float* __restrict__ b,
                                                     float* __restrict__ h,
                                                     float* __restrict__ cps,
                                                     float* __restrict__ cpq, int n) {
    __shared__ float4 ssum[256];
    __shared__ float4 ssq[256];
    int t = threadIdx.x;
    int lane = t & 31;
    int grp = t >> 5;  // 8 groups of 32
    int v = blockIdx.x * 8 + grp;
    float4 lsum = make_float4(0.f, 0.f, 0.f, 0.f);
    float4 lsq = make_float4(0.f, 0.f, 0.f, 0.f);

    if (v < n) {
        int deg = cnt[v];
        float dv = rsqrtf((float)deg + 1.0f);  // +1 self-loop
        int m_all = deg < CAP ? deg : CAP;
        float4 acc = load_row_f16(lin_h, v, lane);
        float dv2 = dv * dv;
        acc.x *= dv2; acc.y *= dv2; acc.z *= dv2; acc.w *= dv2;
        const int* brow = bucket + (long long)v * CAP;

        for (int jb = 0; jb < m_all; jb += 32) {
            int j = jb + lane;
            int idx = (j < m_all) ? brow[j] : 0;
            float dn = (j < m_all) ? rsqrtf((float)cnt[idx] + 1.0f) * dv : 0.f;
            int m = m_all - jb;
            if (m > 32) m = 32;
            int k = 0;
            for (; k + 8 <= m; k += 8) {
                int s0 = __shfl(idx, k + 0, 32); float n0 = __shfl(dn, k + 0, 32);
                int s1 = __shfl(idx, k + 1, 32); float n1 = __shfl(dn, k + 1, 32);
                int s2 = __shfl(idx, k + 2, 32); float n2 = __shfl(dn, k + 2, 32);
                int s3 = __shfl(idx, k + 3, 32); float n3 = __shfl(dn, k + 3, 32);
                int s4 = __shfl(idx, k + 4, 32); float n4 = __shfl(dn, k + 4, 32);
                int s5 = __shfl(idx, k + 5, 32); float n5 = __shfl(dn, k + 5, 32);
                int s6 = __shfl(idx, k + 6, 32); float n6 = __shfl(dn, k + 6, 32);
                int s7 = __shfl(idx, k + 7, 32); float n7 = __shfl(dn, k + 7, 32);
                float4 v0 = load_row_f16(lin_h, s0, lane);
                float4 v1 = load_row_f16(lin_h, s1, lane);
                float4 v2 = load_row_f16(lin_h, s2, lane);
                float4 v3 = load_row_f16(lin_h, s3, lane);
                float4 v4 = load_row_f16(lin_h, s4, lane);
                float4 v5 = load_row_f16(lin_h, s5, lane);
                float4 v6 = load_row_f16(lin_h, s6, lane);
                float4 v7 = load_row_f16(lin_h, s7, lane);
                acc.x += v0.x * n0 + v1.x * n1 + v2.x * n2 + v3.x * n3
                       + v4.x * n4 + v5.x * n5 + v6.x * n6 + v7.x * n7;
                acc.y += v0.y * n0 + v1.y * n1 + v2.y * n2 + v3.y * n3
                       + v4.y * n4 + v5.y * n5 + v6.y * n6 + v7.y * n7;
                acc.z += v0.z * n0 + v1.z * n1 + v2.z * n2 + v3.z * n3
                       + v4.z * n4 + v5.z * n5 + v6.z * n6 + v7.z * n7;
                acc.w += v0.w * n0 + v1.w * n1 + v2.w * n2 + v3.w * n3
                       + v4.w * n4 + v5.w * n5 + v6.w * n6 + v7.w * n7;
            }
            for (; k + 4 <= m; k += 4) {
                int s0 = __shfl(idx, k + 0, 32); float n0 = __shfl(dn, k + 0, 32);
                int s1 = __shfl(idx, k + 1, 32); float n1 = __shfl(dn, k + 1, 32);
                int s2 = __shfl(idx, k + 2, 32); float n2 = __shfl(dn, k + 2, 32);
                int s3 = __shfl(idx, k + 3, 32); float n3 = __shfl(dn, k + 3, 32);
                float4 v0 = load_row_f16(lin_h, s0, lane);
                float4 v1 = load_row_f16(lin_h, s1, lane);
                float4 v2 = load_row_f16(lin_h, s2, lane);
                float4 v3 = load_row_f16(lin_h, s3, lane);
                acc.x += v0.x * n0 + v1.x * n1 + v2.x * n2 + v3.x * n3;
                acc.y += v0.y * n0 + v1.y * n1 + v2.y * n2 + v3.y * n3;
                acc.z += v0.z * n0 + v1.z * n1 + v2.z * n2 + v3.z * n3;
                acc.w += v0.w * n0 + v1.w * n1 + v2.w * n2 + v3.w * n3;
            }
            for (; k < m; ++k) {
                int s0 = __shfl(idx, k, 32);
                float n0 = __shfl(dn, k, 32);
                float4 v0 = load_row_f16(lin_h, s0, lane);
                acc.x += v0.x * n0;
                acc.y += v0.y * n0;
                acc.z += v0.z * n0;
                acc.w += v0.w * n0;
            }
        }
        float4 bb = ((const float4*)b)[lane];
        acc.x += bb.x; acc.y += bb.y; acc.z += bb.z; acc.w += bb.w;
        ((float4*)(h + (long long)v * 128))[lane] = acc;
        lsum = acc;
        lsq = make_float4(acc.x * acc.x, acc.y * acc.y, acc.z * acc.z, acc.w * acc.w);
    }

    ssum[t] = lsum;
    ssq[t] = lsq;
    __syncthreads();
    if (t < 32) {
        float4 a = ssum[t];
        float4 q = ssq[t];
        for (int g2 = 1; g2 < 8; ++g2) {
            float4 a2 = ssum[g2 * 32 + t];
            float4 q2 = ssq[g2 * 32 + t];
            a.x += a2.x; a.y += a2.y; a.z += a2.z; a.w += a2.w;
            q.x += q2.x; q.y += q2.y; q.z += q2.z; q.w += q2.w;
        }
        int rep = (blockIdx.x & (NREP - 1)) * 128;
        atomicAdd(&cps[rep + t * 4 + 0], a.x);
        atomicAdd(&cps[rep + t * 4 + 1], a.y);
        atomicAdd(&cps[rep + t * 4 + 2], a.z);
        atomicAdd(&cps[rep + t * 4 + 3], a.w);
        atomicAdd(&cpq[rep + t * 4 + 0], q.x);
        atomicAdd(&cpq[rep + t * 4 + 1], q.y);
        atomicAdd(&cpq[rep + t * 4 + 2], q.z);
        atomicAdd(&cpq[rep + t * 4 + 3], q.w);
    }
}

// Merged fixup + BN-stat reduce (one 1-block kernel; both rare-path/tiny).
// Fast path: reduce NREP replicated stats. Slow path (overflow): apply
// overflow edges to h, then re-stream h for exact stats.
__global__ __launch_bounds__(256) void finalize_kernel(const int* __restrict__ ovf_cnt,
                                                       const int* __restrict__ ovf_list,
                                                       const int* __restrict__ cnt,
                                                       const __half* __restrict__ lin_h,
                                                       float* __restrict__ h,
                                                       const float* __restrict__ cps,
                                                       const float* __restrict__ cpq,
                                                       const float* __restrict__ gamma,
                                                       const float* __restrict__ beta,
                                                       float* __restrict__ scale,
                                                       float* __restrict__ shift, int n) {
    __shared__ float s0[256];
    __shared__ float s1[256];
    int t = threadIdx.x;
    int nov = *ovf_cnt;
    if (nov > OVF_CAP) nov = OVF_CAP;
    if (nov > 0) {
        int lane = t & 31;
        int grp = t >> 5;
        for (int i = grp; i < nov; i += 8) {
            int dst = ovf_list[2 * i];
            int src = ovf_list[2 * i + 1];
            float norm = rsqrtf((float)cnt[src] + 1.0f) * rsqrtf((float)cnt[dst] + 1.0f);
            float4 v0 = load_row_f16(lin_h, src, lane);
            float* hp = h + (long long)dst * 128 + lane * 4;
            atomicAdd(hp + 0, v0.x * norm);
            atomicAdd(hp + 1, v0.y * norm);
            atomicAdd(hp + 2, v0.z * norm);
            atomicAdd(hp + 3, v0.w * norm);
        }
        __threadfence();
    }
    __syncthreads();

    int col = t & 127;
    int hf = t >> 7;
    float s = 0.f, q = 0.f;
    if (nov == 0) {
        for (int r = hf * (NREP / 2); r < (hf + 1) * (NREP / 2); ++r) {
            s += cps[r * 128 + col];
            q += cpq[r * 128 + col];
        }
    } else {
        for (long long r = hf; r < n; r += 2) {
            float hv = h[r * 128 + col];
            s += hv;
            q += hv * hv;
        }
    }
    s0[t] = s;
    s1[t] = q;
    __syncthreads();
    if (t < 128) {
        float su = s0[t] + s0[t + 128];
        float qu = s1[t] + s1[t + 128];
        float m = su / (float)n;
        float var = qu / (float)n - m * m;
        float sc = gamma[t] * rsqrtf(var + BN_EPS);
        scale[t] = sc;
        shift[t] = beta[t] - m * sc;
    }
}

// out = relu(h*scale + shift) + x
__global__ __launch_bounds__(256) void out_kernel(const float* __restrict__ h,
                                                  const float* __restrict__ x,
                                                  const float* __restrict__ scale,
                                                  const float* __restrict__ shift,
                                                  float* __restrict__ out, int n) {
    long long total4 = (long long)n * 32;
    long long i = (long long)blockIdx.x * 256 + threadIdx.x;
    long long stride = (long long)gridDim.x * 256;
    for (; i < total4; i += stride) {
        int c4 = (int)(i & 31);
        float4 sc = ((const float4*)scale)[c4];
        float4 sh = ((const float4*)shift)[c4];
        float4 hv = ((const float4*)h)[i];
        float4 xv = ((const float4*)x)[i];
        float4 o;
        o.x = fmaxf(hv.x * sc.x + sh.x, 0.f) + xv.x;
        o.y = fmaxf(hv.y * sc.y + sh.y, 0.f) + xv.y;
        o.z = fmaxf(hv.z * sc.z + sh.z, 0.f) + xv.z;
        o.w = fmaxf(hv.w * sc.w + sh.w, 0.f) + xv.w;
        ((float4*)out)[i] = o;
    }
}

extern "C" void kernel_launch(void* const* d_in, const int* in_sizes, int n_in,
                              void* d_out, int out_size, void* d_ws, size_t ws_size,
                              hipStream_t stream) {
    const float* x     = (const float*)d_in[0];
    const void*  eidx  = d_in[1];
    const float* W     = (const float*)d_in[2];
    const float* b     = (const float*)d_in[3];
    const float* gamma = (const float*)d_in[4];
    const float* beta  = (const float*)d_in[5];
    float* out = (float*)d_out;

    int n = in_sizes[0] / 128;
    int E = in_sizes[1] / 2;

    float* ws = (float*)d_ws;
    long long nd = (long long)n * 128;
    __half* lin_h   = (__half*)ws;                    // n*64 floats worth
    float* h        = ws + (long long)n * 64;
    int*   cnt      = (int*)(h + nd);
    float* cps      = (float*)(cnt + n);
    float* cpq      = cps + NREP * 128;
    int*   ovf_cnt  = (int*)(cpq + NREP * 128);
    int*   flag     = ovf_cnt + 1;
    int*   ovf_list = flag + 1;
    int*   bucket   = ovf_list + 2 * OVF_CAP;
    float* scale    = (float*)(bucket + (long long)n * CAP);
    float* shift    = scale + 128;

    // zero range: cnt + cps + cpq + ovf_cnt (contiguous)
    int zcount = n + 2 * NREP * 128 + 1;
    prep_kernel<<<64, 256, 0, stream>>>((const unsigned*)eidx, cnt, zcount, flag);

    fill_kernel<<<(E + 255) / 256, 256, 0, stream>>>(eidx, flag, cnt, bucket,
                                                     ovf_cnt, ovf_list, E);

    gemm_kernel<<<768, 256, 0, stream>>>(x, W, lin_h, n);

    gather_kernel<<<(n + 7) / 8, 256, 0, stream>>>(cnt, bucket, lin_h, b, h,
                                                   cps, cpq, n);

    finalize_kernel<<<1, 256, 0, stream>>>(ovf_cnt, ovf_list, cnt, lin_h, h,
                                           cps, cpq, gamma, beta, scale, shift, n);

    out_kernel<<<2048, 256, 0, stream>>>(h, x, scale, shift, out, n);
}

// Round 10
// 180.741 us; speedup vs baseline: 2.8462x; 1.1349x over previous
//
#include <hip/hip_runtime.h>
#include <hip/hip_fp16.h>

#define BN_EPS 1e-5f
#define CAP 64          // bucket capacity per node (deg ~ Poisson(12); P(>64) ~ 1e-30)
#define OVF_CAP 65536   // overflow edge list capacity
#define NREP 64         // replicated BN-stat accumulators

typedef _Float16 f16x8 __attribute__((ext_vector_type(8)));
typedef float f32x4 __attribute__((ext_vector_type(4)));

// ---------------------------------------------------------------------------
// ws layout (4-byte units):
//   lin_h   [n*64]   (half[n*128], x@W in fp16)
//   h       [n*128]  float (pre-BN activations)
//   cnt     [n]      int   (degree counters; zeroed)
//   cps     [NREP*128] float (replicated col sums; zeroed)
//   cpq     [NREP*128] float (replicated col sumsq; zeroed)
//   ovf_cnt [1]      int   (zeroed)
//   flag    [1]      int   (1 if edge_index is int64)
//   ovf_list[2*OVF_CAP] int
//   bucket  [n*CAP]  int
//   scale   [128], shift [128] float
// ---------------------------------------------------------------------------

// zero cnt+cps+cpq+ovf_cnt; block 0 detects int32-vs-int64 edge dtype.
__global__ __launch_bounds__(256) void prep_kernel(const unsigned* __restrict__ e32,
                                                   int* __restrict__ zbase, int zcount,
                                                   int* __restrict__ flag) {
    int i = blockIdx.x * 256 + threadIdx.x;
    for (; i < zcount; i += gridDim.x * 256) zbase[i] = 0;
    if (blockIdx.x == 0 && threadIdx.x < 64) {
        // int64 indices < 2^31: every odd 32-bit word is 0.
        unsigned v = e32[2 * threadIdx.x + 1];
        unsigned long long b = __ballot(v == 0u);
        if (threadIdx.x == 0) *flag = (b == ~0ULL) ? 1 : 0;
    }
}

// count degree + place src into dst's bucket row in one atomic. 1 edge/thread.
__global__ __launch_bounds__(256) void fill_kernel(const void* __restrict__ eidx,
                                                   const int* __restrict__ flag,
                                                   int* __restrict__ cnt,
                                                   int* __restrict__ bucket,
                                                   int* __restrict__ ovf_cnt,
                                                   int* __restrict__ ovf_list, int E) {
    int e = blockIdx.x * 256 + threadIdx.x;
    if (e >= E) return;
    int src, dst;
    if (*flag) {
        const long long* p = (const long long*)eidx;
        src = (int)p[e];
        dst = (int)p[(long long)E + e];
    } else {
        const int* p = (const int*)eidx;
        src = p[e];
        dst = p[E + e];
    }
    int pos = atomicAdd(&cnt[dst], 1);
    if (pos < CAP) {
        bucket[(long long)dst * CAP + pos] = src;
    } else {
        int o = atomicAdd(ovf_cnt, 1);
        if (o < OVF_CAP) { ovf_list[2 * o] = dst; ovf_list[2 * o + 1] = src; }
    }
}

// lin_h = fp16(x @ W) via MFMA 16x16x32_f16 with split precision:
//   x = xh + xl, W = Wh + Wl (fp16 hi + fp16 residual)
//   lin = xh*Wh + xh*Wl + xl*Wh   (dropped xl*Wl ~ 2e-7 relative)
// Per block: 4 waves x 16 rows = 64 rows; full 128 cols per wave (8 col-tiles).
// W staged once per block in fragment-linear LDS (Whi+Wlo = 64 KB -> 2 blocks/CU).
// A fragments loaded direct from global (x has no cross-block reuse).
// Verified fragment maps (learn_hip m89/m91): A/B: 16-dim = lane&15,
// k = 8*(lane>>4)+i;  D: col = lane&15, row = (lane>>4)*4 + reg.
__global__ __launch_bounds__(256, 2) void gemm_kernel(const float* __restrict__ x,
                                                      const float* __restrict__ W,
                                                      __half* __restrict__ lin_h, int n) {
    __shared__ _Float16 Whi[16384];  // 32 KB, fragment-linear: [(s*8+c)*64 + lane] x 8
    __shared__ _Float16 Wlo[16384];  // 32 KB
    int t = threadIdx.x;

    for (int ent = t; ent < 2048; ent += 256) {
        int f = ent >> 6;            // frag id: f = s*8 + c
        int l = ent & 63;
        int s = f >> 3, c = f & 7;
        int k0 = s * 32 + ((l >> 4) << 3);
        int col = c * 16 + (l & 15);
        f16x8 hi, lo;
#pragma unroll
        for (int i = 0; i < 8; ++i) {
            float wv = W[(k0 + i) * 128 + col];
            _Float16 hh = (_Float16)wv;
            hi[i] = hh;
            lo[i] = (_Float16)(wv - (float)hh);
        }
        ((f16x8*)Whi)[ent] = hi;
        ((f16x8*)Wlo)[ent] = lo;
    }
    __syncthreads();

    int wid = t >> 6;
    int l = t & 63;
    int r0 = blockIdx.x * 64 + wid * 16;
    int arow = r0 + (l & 15);
    int kbase = (l >> 4) << 3;
    bool av = arow < n;
    const float* xr = x + (long long)arow * 128;

    f32x4 acc[8];
#pragma unroll
    for (int c = 0; c < 8; ++c) acc[c] = (f32x4){0.f, 0.f, 0.f, 0.f};

#pragma unroll
    for (int s = 0; s < 4; ++s) {
        f16x8 ah, al;
        if (av) {
            const float* xp = xr + s * 32 + kbase;
            float4 u0 = *(const float4*)(xp);
            float4 u1 = *(const float4*)(xp + 4);
            float xv[8] = {u0.x, u0.y, u0.z, u0.w, u1.x, u1.y, u1.z, u1.w};
#pragma unroll
            for (int i = 0; i < 8; ++i) {
                _Float16 hh = (_Float16)xv[i];
                ah[i] = hh;
                al[i] = (_Float16)(xv[i] - (float)hh);
            }
        } else {
#pragma unroll
            for (int i = 0; i < 8; ++i) { ah[i] = (_Float16)0.f; al[i] = (_Float16)0.f; }
        }
#pragma unroll
        for (int c = 0; c < 8; ++c) {
            f16x8 bh = ((const f16x8*)Whi)[(s * 8 + c) * 64 + l];
            f16x8 bl = ((const f16x8*)Wlo)[(s * 8 + c) * 64 + l];
            acc[c] = __builtin_amdgcn_mfma_f32_16x16x32_f16(ah, bh, acc[c], 0, 0, 0);
            acc[c] = __builtin_amdgcn_mfma_f32_16x16x32_f16(ah, bl, acc[c], 0, 0, 0);
            acc[c] = __builtin_amdgcn_mfma_f32_16x16x32_f16(al, bh, acc[c], 0, 0, 0);
        }
    }

    int orow0 = r0 + ((l >> 4) << 2);
    int ocol = l & 15;
#pragma unroll
    for (int j = 0; j < 4; ++j) {
        int orow = orow0 + j;
        if (orow < n) {
            __half* op = lin_h + (long long)orow * 128 + ocol;
#pragma unroll
            for (int c = 0; c < 8; ++c)
                op[c * 16] = __float2half((float)acc[c][j]);
        }
    }
}

__device__ __forceinline__ float4 load_row_f16(const __half* __restrict__ lin_h,
                                               long long row, int lane) {
    uint2 raw = ((const uint2*)(lin_h + row * 128))[lane];
    float2 f0 = __half22float2(*(__half2*)&raw.x);
    float2 f1 = __half22float2(*(__half2*)&raw.y);
    return make_float4(f0.x, f0.y, f1.x, f1.y);
}

// One 32-lane group per node; dinv computed on the fly from cnt.
// h[v] = sum_{s in bucket(v)} lin[s]*dinv[s]*dinv[v] + lin[v]*dinv[v]^2 + b
// BN col-stats accumulated into NREP replicated slots (no serial tail).
__global__ __launch_bounds__(256) void gather_kernel(const int* __restrict__ cnt,
                                                     const int* __restrict__ bucket,
                                                     const __half* __restrict__ lin_h,
                                                     const float* __restrict__ b,
                                                     float* __restrict__ h,
                                                     float* __restrict__ cps,
                                                     float* __restrict__ cpq, int n) {
    __shared__ float4 ssum[256];
    __shared__ float4 ssq[256];
    int t = threadIdx.x;
    int lane = t & 31;
    int grp = t >> 5;  // 8 groups of 32
    int v = blockIdx.x * 8 + grp;
    float4 lsum = make_float4(0.f, 0.f, 0.f, 0.f);
    float4 lsq = make_float4(0.f, 0.f, 0.f, 0.f);

    if (v < n) {
        int deg = cnt[v];
        float dv = rsqrtf((float)deg + 1.0f);  // +1 self-loop
        int m_all = deg < CAP ? deg : CAP;
        float4 acc = load_row_f16(lin_h, v, lane);
        float dv2 = dv * dv;
        acc.x *= dv2; acc.y *= dv2; acc.z *= dv2; acc.w *= dv2;
        const int* brow = bucket + (long long)v * CAP;

        for (int jb = 0; jb < m_all; jb += 32) {
            int j = jb + lane;
            int idx = (j < m_all) ? brow[j] : 0;
            float dn = (j < m_all) ? rsqrtf((float)cnt[idx] + 1.0f) * dv : 0.f;
            int m = m_all - jb;
            if (m > 32) m = 32;
            int k = 0;
            for (; k + 8 <= m; k += 8) {
                int s0 = __shfl(idx, k + 0, 32); float n0 = __shfl(dn, k + 0, 32);
                int s1 = __shfl(idx, k + 1, 32); float n1 = __shfl(dn, k + 1, 32);
                int s2 = __shfl(idx, k + 2, 32); float n2 = __shfl(dn, k + 2, 32);
                int s3 = __shfl(idx, k + 3, 32); float n3 = __shfl(dn, k + 3, 32);
                int s4 = __shfl(idx, k + 4, 32); float n4 = __shfl(dn, k + 4, 32);
                int s5 = __shfl(idx, k + 5, 32); float n5 = __shfl(dn, k + 5, 32);
                int s6 = __shfl(idx, k + 6, 32); float n6 = __shfl(dn, k + 6, 32);
                int s7 = __shfl(idx, k + 7, 32); float n7 = __shfl(dn, k + 7, 32);
                float4 v0 = load_row_f16(lin_h, s0, lane);
                float4 v1 = load_row_f16(lin_h, s1, lane);
                float4 v2 = load_row_f16(lin_h, s2, lane);
                float4 v3 = load_row_f16(lin_h, s3, lane);
                float4 v4 = load_row_f16(lin_h, s4, lane);
                float4 v5 = load_row_f16(lin_h, s5, lane);
                float4 v6 = load_row_f16(lin_h, s6, lane);
                float4 v7 = load_row_f16(lin_h, s7, lane);
                acc.x += v0.x * n0 + v1.x * n1 + v2.x * n2 + v3.x * n3
                       + v4.x * n4 + v5.x * n5 + v6.x * n6 + v7.x * n7;
                acc.y += v0.y * n0 + v1.y * n1 + v2.y * n2 + v3.y * n3
                       + v4.y * n4 + v5.y * n5 + v6.y * n6 + v7.y * n7;
                acc.z += v0.z * n0 + v1.z * n1 + v2.z * n2 + v3.z * n3
                       + v4.z * n4 + v5.z * n5 + v6.z * n6 + v7.z * n7;
                acc.w += v0.w * n0 + v1.w * n1 + v2.w * n2 + v3.w * n3
                       + v4.w * n4 + v5.w * n5 + v6.w * n6 + v7.w * n7;
            }
            for (; k + 4 <= m; k += 4) {
                int s0 = __shfl(idx, k + 0, 32); float n0 = __shfl(dn, k + 0, 32);
                int s1 = __shfl(idx, k + 1, 32); float n1 = __shfl(dn, k + 1, 32);
                int s2 = __shfl(idx, k + 2, 32); float n2 = __shfl(dn, k + 2, 32);
                int s3 = __shfl(idx, k + 3, 32); float n3 = __shfl(dn, k + 3, 32);
                float4 v0 = load_row_f16(lin_h, s0, lane);
                float4 v1 = load_row_f16(lin_h, s1, lane);
                float4 v2 = load_row_f16(lin_h, s2, lane);
                float4 v3 = load_row_f16(lin_h, s3, lane);
                acc.x += v0.x * n0 + v1.x * n1 + v2.x * n2 + v3.x * n3;
                acc.y += v0.y * n0 + v1.y * n1 + v2.y * n2 + v3.y * n3;
                acc.z += v0.z * n0 + v1.z * n1 + v2.z * n2 + v3.z * n3;
                acc.w += v0.w * n0 + v1.w * n1 + v2.w * n2 + v3.w * n3;
            }
            for (; k < m; ++k) {
                int s0 = __shfl(idx, k, 32);
                float n0 = __shfl(dn, k, 32);
                float4 v0 = load_row_f16(lin_h, s0, lane);
                acc.x += v0.x * n0;
                acc.y += v0.y * n0;
                acc.z += v0.z * n0;
                acc.w += v0.w * n0;
            }
        }
        float4 bb = ((const float4*)b)[lane];
        acc.x += bb.x; acc.y += bb.y; acc.z += bb.z; acc.w += bb.w;
        ((float4*)(h + (long long)v * 128))[lane] = acc;
        lsum = acc;
        lsq = make_float4(acc.x * acc.x, acc.y * acc.y, acc.z * acc.z, acc.w * acc.w);
    }

    ssum[t] = lsum;
    ssq[t] = lsq;
    __syncthreads();
    if (t < 32) {
        float4 a = ssum[t];
        float4 q = ssq[t];
        for (int g2 = 1; g2 < 8; ++g2) {
            float4 a2 = ssum[g2 * 32 + t];
            float4 q2 = ssq[g2 * 32 + t];
            a.x += a2.x; a.y += a2.y; a.z += a2.z; a.w += a2.w;
            q.x += q2.x; q.y += q2.y; q.z += q2.z; q.w += q2.w;
        }
        int rep = (blockIdx.x & (NREP - 1)) * 128;
        atomicAdd(&cps[rep + t * 4 + 0], a.x);
        atomicAdd(&cps[rep + t * 4 + 1], a.y);
        atomicAdd(&cps[rep + t * 4 + 2], a.z);
        atomicAdd(&cps[rep + t * 4 + 3], a.w);
        atomicAdd(&cpq[rep + t * 4 + 0], q.x);
        atomicAdd(&cpq[rep + t * 4 + 1], q.y);
        atomicAdd(&cpq[rep + t * 4 + 2], q.z);
        atomicAdd(&cpq[rep + t * 4 + 3], q.w);
    }
}

// Merged fixup + BN-stat reduce (one 1-block kernel; both rare-path/tiny).
// Fast path: reduce NREP replicated stats. Slow path (overflow): apply
// overflow edges to h, then re-stream h for exact stats.
__global__ __launch_bounds__(256) void finalize_kernel(const int* __restrict__ ovf_cnt,
                                                       const int* __restrict__ ovf_list,
                                                       const int* __restrict__ cnt,
                                                       const __half* __restrict__ lin_h,
                                                       float* __restrict__ h,
                                                       const float* __restrict__ cps,
                                                       const float* __restrict__ cpq,
                                                       const float* __restrict__ gamma,
                                                       const float* __restrict__ beta,
                                                       float* __restrict__ scale,
                                                       float* __restrict__ shift, int n) {
    __shared__ float s0[256];
    __shared__ float s1[256];
    int t = threadIdx.x;
    int nov = *ovf_cnt;
    if (nov > OVF_CAP) nov = OVF_CAP;
    if (nov > 0) {
        int lane = t & 31;
        int grp = t >> 5;
        for (int i = grp; i < nov; i += 8) {
            int dst = ovf_list[2 * i];
            int src = ovf_list[2 * i + 1];
            float norm = rsqrtf((float)cnt[src] + 1.0f) * rsqrtf((float)cnt[dst] + 1.0f);
            float4 v0 = load_row_f16(lin_h, src, lane);
            float* hp = h + (long long)dst * 128 + lane * 4;
            atomicAdd(hp + 0, v0.x * norm);
            atomicAdd(hp + 1, v0.y * norm);
            atomicAdd(hp + 2, v0.z * norm);
            atomicAdd(hp + 3, v0.w * norm);
        }
        __threadfence();
    }
    __syncthreads();

    int col = t & 127;
    int hf = t >> 7;
    float s = 0.f, q = 0.f;
    if (nov == 0) {
        for (int r = hf * (NREP / 2); r < (hf + 1) * (NREP / 2); ++r) {
            s += cps[r * 128 + col];
            q += cpq[r * 128 + col];
        }
    } else {
        for (long long r = hf; r < n; r += 2) {
            float hv = h[r * 128 + col];
            s += hv;
            q += hv * hv;
        }
    }
    s0[t] = s;
    s1[t] = q;
    __syncthreads();
    if (t < 128) {
        float su = s0[t] + s0[t + 128];
        float qu = s1[t] + s1[t + 128];
        float m = su / (float)n;
        float var = qu / (float)n - m * m;
        float sc = gamma[t] * rsqrtf(var + BN_EPS);
        scale[t] = sc;
        shift[t] = beta[t] - m * sc;
    }
}

// out = relu(h*scale + shift) + x
__global__ __launch_bounds__(256) void out_kernel(const float* __restrict__ h,
                                                  const float* __restrict__ x,
                                                  const float* __restrict__ scale,
                                                  const float* __restrict__ shift,
                                                  float* __restrict__ out, int n) {
    long long total4 = (long long)n * 32;
    long long i = (long long)blockIdx.x * 256 + threadIdx.x;
    long long stride = (long long)gridDim.x * 256;
    for (; i < total4; i += stride) {
        int c4 = (int)(i & 31);
        float4 sc = ((const float4*)scale)[c4];
        float4 sh = ((const float4*)shift)[c4];
        float4 hv = ((const float4*)h)[i];
        float4 xv = ((const float4*)x)[i];
        float4 o;
        o.x = fmaxf(hv.x * sc.x + sh.x, 0.f) + xv.x;
        o.y = fmaxf(hv.y * sc.y + sh.y, 0.f) + xv.y;
        o.z = fmaxf(hv.z * sc.z + sh.z, 0.f) + xv.z;
        o.w = fmaxf(hv.w * sc.w + sh.w, 0.f) + xv.w;
        ((float4*)out)[i] = o;
    }
}

extern "C" void kernel_launch(void* const* d_in, const int* in_sizes, int n_in,
                              void* d_out, int out_size, void* d_ws, size_t ws_size,
                              hipStream_t stream) {
    const float* x     = (const float*)d_in[0];
    const void*  eidx  = d_in[1];
    const float* W     = (const float*)d_in[2];
    const float* b     = (const float*)d_in[3];
    const float* gamma = (const float*)d_in[4];
    const float* beta  = (const float*)d_in[5];
    float* out = (float*)d_out;

    int n = in_sizes[0] / 128;
    int E = in_sizes[1] / 2;

    float* ws = (float*)d_ws;
    long long nd = (long long)n * 128;
    __half* lin_h   = (__half*)ws;                    // n*64 floats worth
    float* h        = ws + (long long)n * 64;
    int*   cnt      = (int*)(h + nd);
    float* cps      = (float*)(cnt + n);
    float* cpq      = cps + NREP * 128;
    int*   ovf_cnt  = (int*)(cpq + NREP * 128);
    int*   flag     = ovf_cnt + 1;
    int*   ovf_list = flag + 1;
    int*   bucket   = ovf_list + 2 * OVF_CAP;
    float* scale    = (float*)(bucket + (long long)n * CAP);
    float* shift    = scale + 128;

    // zero range: cnt + cps + cpq + ovf_cnt (contiguous)
    int zcount = n + 2 * NREP * 128 + 1;
    prep_kernel<<<64, 256, 0, stream>>>((const unsigned*)eidx, cnt, zcount, flag);

    fill_kernel<<<(E + 255) / 256, 256, 0, stream>>>(eidx, flag, cnt, bucket,
                                                     ovf_cnt, ovf_list, E);

    gemm_kernel<<<(n + 63) / 64, 256, 0, stream>>>(x, W, lin_h, n);

    gather_kernel<<<(n + 7) / 8, 256, 0, stream>>>(cnt, bucket, lin_h, b, h,
                                                   cps, cpq, n);

    finalize_kernel<<<1, 256, 0, stream>>>(ovf_cnt, ovf_list, cnt, lin_h, h,
                                           cps, cpq, gamma, beta, scale, shift, n);

    out_kernel<<<2048, 256, 0, stream>>>(h, x, scale, shift, out, n);
}